// Round 4
// baseline (213.556 us; speedup 1.0000x reference)
//
#include <hip/hip_runtime.h>
#include <hip/hip_bf16.h>
#include <math.h>

#define NN 1024
#define LDIM 32
#define HDIM 64

// ---------------- fp32 workspace layout (float offsets) ----------------
#define WS_SELF 0                        // N*L   self_term [i][l]
#define WS_AA   (WS_SELF + NN*LDIM)      // N*H   a_i [i][h]
#define WS_CI   (WS_AA   + NN*HDIM)      // N*L   ci [i][l]
#define WS_AGG  (WS_CI   + NN*LDIM)      // N     sigmoid(aggr)
#define WS_BI2  (WS_AGG  + NN)           // H
#define WS_BI3  (WS_BI2  + HDIM)         // L
#define WS_BCB  (WS_BI3  + LDIM)         // L     bc
#define WS_FEND (WS_BCB  + LDIM)         // 132224 floats = 528896 B

// ---------------- bf16(u16) region (short offsets from wsu) -------------
#define U_BJB  0                         // N*H   b_j [j][h]
#define U_HJB  (U_BJB + NN*HDIM)         // N*L   h   [j][l]
#define U_JT   (U_HJB + NN*LDIM)         // N*L*4 interleaved {h,cj | pc,ps}
#define U_W2B  (U_JT  + NN*LDIM*4)       // H*H   Wi2 [n][k]
#define U_W3B  (U_W2B + HDIM*HDIM)       // L*H   Wi3 [l][k]
#define U_END  (U_W3B + LDIM*HDIM)       // 235520 shorts

// packed-pair transposed weight tables for precompute (uint offsets in wpk)
#define PK_W1  0        // 16*64   Ws1:  pair(2k,2k+1) x feature
#define PK_W2  1024     // 32*64   Ws2
#define PK_W3  3072     // 32*32   Ws3
#define PK_WI1 4096     // 64*64   Wi1 (col-pair x feature)
#define PK_WC  8192     // 32*32   Wc
#define PK_END 9216

typedef __attribute__((ext_vector_type(8))) short bf16x8;
typedef __attribute__((ext_vector_type(4))) float f32x4;

__device__ __forceinline__ float fast_rcp(float x) { return __builtin_amdgcn_rcpf(x); }
__device__ __forceinline__ float fast_tanh(float x) {
    float e = __builtin_amdgcn_exp2f(x * 2.88539008f);   // exp(2x)
    return 1.0f - 2.0f * fast_rcp(e + 1.0f);             // saturates cleanly
}
__device__ __forceinline__ float fast_sigmoid(float x) {
    return fast_rcp(1.0f + __builtin_amdgcn_exp2f(x * -1.44269504f));
}
// bf16 halves of a packed uint -> f32 (exact)
__device__ __forceinline__ float blo(unsigned int u) { union { unsigned int i; float f; } v; v.i = u << 16; return v.f; }
__device__ __forceinline__ float bhi(unsigned int u) { union { unsigned int i; float f; } v; v.i = u & 0xffff0000u; return v.f; }
__device__ __forceinline__ float bf2f(unsigned short u) { union { unsigned int i; float f; } v; v.i = ((unsigned int)u) << 16; return v.f; }
__device__ __forceinline__ unsigned short f2bf(float f) {          // HW cvt
    __hip_bfloat16 b = __float2bfloat16(f);
    unsigned short u; __builtin_memcpy(&u, &b, 2); return u;
}
__device__ __forceinline__ unsigned int pk2(float a, float b) {    // HW cvt_pk
    float2 t; t.x = a; t.y = b;
    __hip_bfloat162 h = __float22bfloat162_rn(t);
    unsigned int u; __builtin_memcpy(&u, &h, 4); return u;
}

// ------------- kernel 1: pack/transpose weights (grid 16x256) -------------
__global__ __launch_bounds__(256) void conv_weights(
    const float* __restrict__ Ws1, const float* __restrict__ Ws2,
    const float* __restrict__ Ws3, const float* __restrict__ Wi1,
    const float* __restrict__ Wc,
    const float* __restrict__ Wi2, const float* __restrict__ bi2,
    const float* __restrict__ Wi3, const float* __restrict__ bi3,
    const float* __restrict__ bcp,
    float* __restrict__ ws, unsigned short* __restrict__ wsu,
    unsigned int* __restrict__ wpk) {
    int t = blockIdx.x * 256 + threadIdx.x;
    if (t < HDIM * HDIM) wsu[U_W2B + t] = f2bf(Wi2[t]);
    if (t < LDIM * HDIM) wsu[U_W3B + t] = f2bf(Wi3[t]);
    if (t < HDIM) ws[WS_BI2 + t] = bi2[t];
    if (t < LDIM) { ws[WS_BI3 + t] = bi3[t]; ws[WS_BCB + t] = bcp[t]; }
    if (t < 1024) { int k2 = t >> 6, f = t & 63;   // Ws1: 64x32
        wpk[PK_W1 + t] = pk2(Ws1[f * 32 + 2 * k2], Ws1[f * 32 + 2 * k2 + 1]); }
    if (t < 2048) { int k2 = t >> 6, f = t & 63;   // Ws2: 64x64
        wpk[PK_W2 + t] = pk2(Ws2[f * 64 + 2 * k2], Ws2[f * 64 + 2 * k2 + 1]); }
    if (t < 1024) { int k2 = t >> 5, f = t & 31;   // Ws3: 32x64
        wpk[PK_W3 + t] = pk2(Ws3[f * 64 + 2 * k2], Ws3[f * 64 + 2 * k2 + 1]); }
    if (t < 4096) { int c2 = t >> 6, f = t & 63;   // Wi1: 64x128
        wpk[PK_WI1 + t] = pk2(Wi1[f * 128 + 2 * c2], Wi1[f * 128 + 2 * c2 + 1]); }
    if (t < 1024) { int c2 = t >> 5, f = t & 31;   // Wc: 32x64
        wpk[PK_WC + t] = pk2(Wc[f * 64 + 2 * c2], Wc[f * 64 + 2 * c2 + 1]); }
}

// ------------- kernel 2: precompute, 256 blocks x 4 waves (1 row/wave) ----
__global__ __launch_bounds__(256) void precompute(
    const float* __restrict__ state,
    const float* __restrict__ bs1, const float* __restrict__ bs2,
    const float* __restrict__ bs3, const float* __restrict__ bi1,
    const float* __restrict__ aggr, const float* __restrict__ phw,
    const unsigned int* __restrict__ wpk,
    float* __restrict__ ws, unsigned short* __restrict__ wsu) {
    const int tid = threadIdx.x;
    const int w = tid >> 6, t = tid & 63;
    const int i = blockIdx.x * 4 + w;

    __shared__ unsigned int wlds[PK_END];     // 36 KB packed weights
    __shared__ float shh[4][32], shdh[4][32], sht1[4][64], sht2[4][64];
    __shared__ float shph[4];

    { // stage packed weights, coalesced uint4
        const uint4* src = (const uint4*)wpk;
        uint4* dst = (uint4*)wlds;
        #pragma unroll
        for (int k = 0; k < 9; k++) dst[tid + k * 256] = src[tid + k * 256];
    }
    float sv = (t < 33) ? state[i * 33 + t] : 0.f;
    if (t < 32) shh[w][t] = sv;
    if (t == 32) shph[w] = sv;
    if (t == 33) ws[WS_AGG + i] = fast_sigmoid(aggr[i]);
    __syncthreads();

    // t1 = tanh(Ws1 @ h + bs1)
    {
        float s = bs1[t];
        const unsigned int* W = wlds + PK_W1;
        #pragma unroll
        for (int k2 = 0; k2 < 16; k2++) {
            unsigned int p = W[k2 * 64 + t];
            s = fmaf(blo(p), shh[w][2 * k2], s);
            s = fmaf(bhi(p), shh[w][2 * k2 + 1], s);
        }
        sht1[w][t] = fast_tanh(s);
    }
    __syncthreads();
    // t2 = tanh(Ws2 @ t1 + bs2)
    {
        float s = bs2[t];
        const unsigned int* W = wlds + PK_W2;
        #pragma unroll
        for (int k2 = 0; k2 < 32; k2++) {
            unsigned int p = W[k2 * 64 + t];
            s = fmaf(blo(p), sht1[w][2 * k2], s);
            s = fmaf(bhi(p), sht1[w][2 * k2 + 1], s);
        }
        sht2[w][t] = fast_tanh(s);
    }
    __syncthreads();
    // self = Ws3 @ t2 + bs3
    if (t < 32) {
        float s = bs3[t];
        const unsigned int* W = wlds + PK_W3;
        #pragma unroll
        for (int k2 = 0; k2 < 32; k2++) {
            unsigned int p = W[k2 * 32 + t];
            s = fmaf(blo(p), sht2[w][2 * k2], s);
            s = fmaf(bhi(p), sht2[w][2 * k2 + 1], s);
        }
        ws[WS_SELF + i * 32 + t] = s;
        shdh[w][t] = s;
    }
    __syncthreads();
    // a_i, b_j
    {
        float sa = 0.f, sb = bi1[t];
        const unsigned int* W = wlds + PK_WI1;
        #pragma unroll
        for (int k2 = 0; k2 < 16; k2++) {
            float h0 = shh[w][2 * k2], h1 = shh[w][2 * k2 + 1];
            float d0 = shdh[w][2 * k2], d1 = shdh[w][2 * k2 + 1];
            unsigned int wa  = W[k2 * 64 + t];          // cols 0..31  (h->a)
            unsigned int wb  = W[(16 + k2) * 64 + t];   // cols 32..63 (h->b)
            unsigned int wa2 = W[(32 + k2) * 64 + t];   // cols 64..95 (dh->a)
            unsigned int wb2 = W[(48 + k2) * 64 + t];   // cols 96..127(dh->b)
            sa = fmaf(blo(wa), h0, sa);  sa = fmaf(bhi(wa), h1, sa);
            sb = fmaf(blo(wb), h0, sb);  sb = fmaf(bhi(wb), h1, sb);
            sa = fmaf(blo(wa2), d0, sa); sa = fmaf(bhi(wa2), d1, sa);
            sb = fmaf(blo(wb2), d0, sb); sb = fmaf(bhi(wb2), d1, sb);
        }
        ws[WS_AA + i * 64 + t] = sa;
        wsu[U_BJB + i * 64 + t] = f2bf(sb);
    }
    // ci, cj, phase tables, jtab
    if (t < 32) {
        float si = 0.f, sj = 0.f;
        const unsigned int* W = wlds + PK_WC;
        #pragma unroll
        for (int m2 = 0; m2 < 16; m2++) {
            float h0 = shh[w][2 * m2], h1 = shh[w][2 * m2 + 1];
            unsigned int wi = W[m2 * 32 + t];           // cols 0..31  (h->ci)
            unsigned int wj = W[(16 + m2) * 32 + t];    // cols 32..63 (h->cj)
            si = fmaf(blo(wi), h0, si); si = fmaf(bhi(wi), h1, si);
            sj = fmaf(blo(wj), h0, sj); sj = fmaf(bhi(wj), h1, sj);
        }
        ws[WS_CI + i * 32 + t] = si;
        float h = shh[w][t];
        wsu[U_HJB + i * 32 + t] = f2bf(h);
        float sc, cc;
        __sincosf(shph[w] * phw[t], &sc, &cc);
        uint2 jt; jt.x = pk2(h, sj); jt.y = pk2(cc, sc);
        *(uint2*)(wsu + U_JT + (i * 32 + t) * 4) = jt;
    }
}

// ------------- kernel 3: MFMA pairwise core (1 block per i) ---------------
__global__ __launch_bounds__(256) void pair_kernel(
    const float* __restrict__ ws, const unsigned short* __restrict__ wsu,
    float* __restrict__ out) {
    const int i    = blockIdx.x;
    const int tid  = threadIdx.x;
    const int w    = tid >> 6;
    const int lane = tid & 63;
    const int q    = lane >> 4;
    const int m    = lane & 15;
    const int jw   = w * 16;

    __shared__ unsigned short W2ls[64 * 72];       // Wi2[n][k], stride 72
    __shared__ unsigned short x2ls[4 * 16 * 72];   // per-wave x2 tile
    __shared__ float his[32];
    __shared__ float facw[4][16];                  // per-wave fac
    __shared__ float red[4][32];

    // ---- setup ----
    if (tid < 32) his[tid] = bf2f(wsu[U_HJB + i * 32 + tid]);
    { // Wi2 -> LDS, padded
        int row = tid >> 2, c = (tid & 3) * 16;
        const uint4* s2 = (const uint4*)(wsu + U_W2B + row * 64 + c);
        uint4 d0 = s2[0], d1 = s2[1];
        uint4* dd = (uint4*)(&W2ls[row * 72 + c]);
        dd[0] = d0; dd[1] = d1;
    }
    // hoisted per-lane invariants
    float aV[16];                                  // a_i slices for afrag
    {
        const float* aP = ws + WS_AA + i * 64;
        #pragma unroll
        for (int s = 0; s < 2; s++)
            #pragma unroll
            for (int c = 0; c < 2; c++) {
                float4 v = *(const float4*)(aP + s * 32 + q * 8 + c * 4);
                aV[s * 8 + c * 4 + 0] = v.x; aV[s * 8 + c * 4 + 1] = v.y;
                aV[s * 8 + c * 4 + 2] = v.z; aV[s * 8 + c * 4 + 3] = v.w;
            }
    }
    float bi2v[4];
    #pragma unroll
    for (int nb = 0; nb < 4; nb++) bi2v[nb] = ws[WS_BI2 + nb * 16 + m];
    bf16x8 w3f[2][2];                              // Wi3 fragments (l = lb*16+m)
    #pragma unroll
    for (int lb = 0; lb < 2; lb++)
        #pragma unroll
        for (int s = 0; s < 2; s++)
            w3f[lb][s] = *(const bf16x8*)(wsu + U_W3B + (lb * 16 + m) * 64 + s * 32 + q * 8);
    float hiv[2], cibv[2], picv[2], pisv[2], bi3v[2];
    #pragma unroll
    for (int lb = 0; lb < 2; lb++) {
        int l = lb * 16 + m;
        uint2 jti = *(const uint2*)(wsu + U_JT + (i * 32 + l) * 4);
        hiv[lb] = blo(jti.x);
        picv[lb] = blo(jti.y); pisv[lb] = bhi(jti.y);
        cibv[lb] = ws[WS_CI + i * 32 + l] + ws[WS_BCB + l];
        bi3v[lb] = ws[WS_BI3 + l];
    }
    const float aggi = ws[WS_AGG + i];
    __syncthreads();   // W2ls + his ready

    float accC0 = 0.f, accC1 = 0.f;

    for (int T = 0; T < 16; T++) {
        const int jb = T * 64;

        // 1) per-wave fac for its 16 j (4 lanes per j)
        {
            int jt = lane >> 2, sub = lane & 3;
            int j = jb + jw + jt;
            union { uint4 u4; unsigned int d[4]; } hv;
            hv.u4 = *(const uint4*)(wsu + U_HJB + j * 32 + sub * 8);
            float s = 0.f;
            #pragma unroll
            for (int e = 0; e < 4; e++) {
                float d0 = his[sub * 8 + 2 * e] - blo(hv.d[e]);
                float d1 = his[sub * 8 + 2 * e + 1] - bhi(hv.d[e]);
                s = fmaf(d0, d0, s); s = fmaf(d1, d1, s);
            }
            s += __shfl_xor(s, 1); s += __shfl_xor(s, 2);
            if (sub == 0) {
                float dist = sqrtf(s) + 1e-6f;
                facw[w][jt] = fminf(fast_rcp(dist), 2.0f) * aggi;
            }
        }

        // 2) x1 A-fragments: tanh(a_i[k] + b_j[k]) packed bf16
        const int jm = jb + jw + m;
        bf16x8 afrag[2];
        #pragma unroll
        for (int s = 0; s < 2; s++) {
            union { uint4 u4; unsigned int d[4]; } bv;
            bv.u4 = *(const uint4*)(wsu + U_BJB + jm * 64 + s * 32 + q * 8);
            union { uint4 u4; bf16x8 v; } pkd;
            #pragma unroll
            for (int e = 0; e < 4; e++) {
                float x0 = fast_tanh(aV[s * 8 + 2 * e]     + blo(bv.d[e]));
                float x1 = fast_tanh(aV[s * 8 + 2 * e + 1] + bhi(bv.d[e]));
                ((unsigned int*)&pkd.u4)[e] = pk2(x0, x1);
            }
            afrag[s] = pkd.v;
        }

        // 3) stage A MFMAs: X2 = X1 @ Wi2^T
        f32x4 accA[4];
        #pragma unroll
        for (int nb = 0; nb < 4; nb++) {
            f32x4 acc = {0.f, 0.f, 0.f, 0.f};
            #pragma unroll
            for (int s = 0; s < 2; s++) {
                bf16x8 bfrag = *(const bf16x8*)(&W2ls[(nb * 16 + m) * 72 + s * 32 + q * 8]);
                acc = __builtin_amdgcn_mfma_f32_16x16x32_bf16(afrag[s], bfrag, acc, 0, 0, 0);
            }
            accA[nb] = acc;
        }
        // epilogue A: x2 = tanh(+bi2) -> per-wave LDS tile
        {
            unsigned short* xw = &x2ls[w * 16 * 72];
            #pragma unroll
            for (int nb = 0; nb < 4; nb++) {
                #pragma unroll
                for (int r = 0; r < 4; r++)
                    xw[(q * 4 + r) * 72 + nb * 16 + m] = f2bf(fast_tanh(accA[nb][r] + bi2v[nb]));
            }
        }

        // 4) stage B MFMAs: K = X2 @ Wi3^T  (same-wave LDS round-trip)
        f32x4 accB[2];
        {
            bf16x8 x2f[2];
            #pragma unroll
            for (int s = 0; s < 2; s++)
                x2f[s] = *(const bf16x8*)(&x2ls[(w * 16 + m) * 72 + s * 32 + q * 8]);
            #pragma unroll
            for (int lb = 0; lb < 2; lb++) {
                f32x4 acc = {0.f, 0.f, 0.f, 0.f};
                #pragma unroll
                for (int s = 0; s < 2; s++)
                    acc = __builtin_amdgcn_mfma_f32_16x16x32_bf16(x2f[s], w3f[lb][s], acc, 0, 0, 0);
                accB[lb] = acc;
            }
        }

        // 5) stage C combine + j-accumulate
        float fv[4];
        #pragma unroll
        for (int r = 0; r < 4; r++) fv[r] = facw[w][q * 4 + r];
        #pragma unroll
        for (int lb = 0; lb < 2; lb++) {
            int l = lb * 16 + m;
            float accl = 0.f;
            #pragma unroll
            for (int r = 0; r < 4; r++) {
                int j = jb + jw + q * 4 + r;
                uint2 jt = *(const uint2*)(wsu + U_JT + (j * 32 + l) * 4);
                float hj = blo(jt.x), cj = bhi(jt.x);
                float pjc = blo(jt.y), pjs = bhi(jt.y);
                float pf  = picv[lb] * pjc + pisv[lb] * pjs;
                float coh = fast_sigmoid(cibv[lb] + cj);
                float kv  = accB[lb][r] + bi3v[lb];
                float v   = fv[r] * kv - pf * coh * (hiv[lb] - hj);
                if (j != i) accl += v;
            }
            if (lb == 0) accC0 += accl; else accC1 += accl;
        }
    }

    // ---- final reduction ----
    accC0 += __shfl_xor(accC0, 16); accC0 += __shfl_xor(accC0, 32);
    accC1 += __shfl_xor(accC1, 16); accC1 += __shfl_xor(accC1, 32);
    if (lane < 16) { red[w][m] = accC0; red[w][16 + m] = accC1; }
    __syncthreads();
    if (tid < 32) {
        float isum = red[0][tid] + red[1][tid] + red[2][tid] + red[3][tid];
        out[i * 33 + tid] = 0.5f * ws[WS_SELF + i * 32 + tid] + 0.3f * isum;
        red[0][tid] = fabsf(isum);
    }
    __syncthreads();
    if (tid == 0) {
        float s = 0.f;
        #pragma unroll
        for (int l = 0; l < 32; l++) s += red[0][l];
        out[i * 33 + 32] = 0.1f + 0.05f * s;
    }
}

extern "C" void kernel_launch(void* const* d_in, const int* in_sizes, int n_in,
                              void* d_out, int out_size, void* d_ws, size_t ws_size,
                              hipStream_t stream) {
    const float* state   = (const float*)d_in[0];
    const float* Ws1     = (const float*)d_in[1];
    const float* bs1     = (const float*)d_in[2];
    const float* Ws2     = (const float*)d_in[3];
    const float* bs2     = (const float*)d_in[4];
    const float* Ws3     = (const float*)d_in[5];
    const float* bs3     = (const float*)d_in[6];
    const float* Wi1     = (const float*)d_in[7];
    const float* bi1     = (const float*)d_in[8];
    const float* Wi2     = (const float*)d_in[9];
    const float* bi2     = (const float*)d_in[10];
    const float* Wi3     = (const float*)d_in[11];
    const float* bi3     = (const float*)d_in[12];
    const float* phase_w = (const float*)d_in[13];
    const float* Wc      = (const float*)d_in[14];
    const float* bc      = (const float*)d_in[15];
    const float* aggr    = (const float*)d_in[16];

    float* ws = (float*)d_ws;
    unsigned short* wsu = (unsigned short*)(ws + WS_FEND);
    unsigned int* wpk = (unsigned int*)(wsu + U_END);
    float* out = (float*)d_out;

    conv_weights<<<16, 256, 0, stream>>>(Ws1, Ws2, Ws3, Wi1, Wc,
                                         Wi2, bi2, Wi3, bi3, bc, ws, wsu, wpk);
    precompute<<<256, 256, 0, stream>>>(state, bs1, bs2, bs3, bi1, aggr, phase_w,
                                        wpk, ws, wsu);
    pair_kernel<<<NN, 256, 0, stream>>>(ws, wsu, out);
}

// Round 5
// 209.181 us; speedup vs baseline: 1.0209x; 1.0209x over previous
//
#include <hip/hip_runtime.h>
#include <hip/hip_bf16.h>
#include <math.h>

#define NN 1024
#define LDIM 32
#define HDIM 64

// ---------------- fp32 workspace layout (float offsets) ----------------
#define WS_SELF 0                        // N*L   self_term [i][l]
#define WS_AA   (WS_SELF + NN*LDIM)      // N*H   a_i [i][h]
#define WS_CI   (WS_AA   + NN*HDIM)      // N*L   ci [i][l]
#define WS_AGG  (WS_CI   + NN*LDIM)      // N     sigmoid(aggr)
#define WS_BI2  (WS_AGG  + NN)           // H
#define WS_BI3  (WS_BI2  + HDIM)         // L
#define WS_BCB  (WS_BI3  + LDIM)         // L     bc
#define WS_FEND (WS_BCB  + LDIM)

// ---------------- bf16(u16) region (short offsets from wsu) -------------
#define U_BJB  0                         // N*H   b_j [j][h]
#define U_HJB  (U_BJB + NN*HDIM)         // N*L   h   [j][l]
#define U_JT   (U_HJB + NN*LDIM)         // N*L*4 interleaved {h,cj | pc,ps}
#define U_W2B  (U_JT  + NN*LDIM*4)       // H*H   Wi2 [n][k]
#define U_W3B  (U_W2B + HDIM*HDIM)       // L*H   Wi3 [l][k]
#define U_END  (U_W3B + LDIM*HDIM)

// packed-pair transposed weight tables in precompute LDS (uint offsets)
#define PK_W1  0        // 16*64   Ws1
#define PK_W2  1024     // 32*64   Ws2
#define PK_W3  3072     // 32*32   Ws3
#define PK_WI1 4096     // 64*64   Wi1
#define PK_WC  8192     // 32*32   Wc
#define PK_END 9216     // 36 KB

typedef __attribute__((ext_vector_type(8))) short bf16x8;
typedef __attribute__((ext_vector_type(4))) float f32x4;

__device__ __forceinline__ float fast_rcp(float x) { return __builtin_amdgcn_rcpf(x); }
__device__ __forceinline__ float fast_tanh(float x) {
    float e = __builtin_amdgcn_exp2f(x * 2.88539008f);   // exp(2x)
    return 1.0f - 2.0f * fast_rcp(e + 1.0f);
}
__device__ __forceinline__ float fast_sigmoid(float x) {
    return fast_rcp(1.0f + __builtin_amdgcn_exp2f(x * -1.44269504f));
}
__device__ __forceinline__ float blo(unsigned int u) { union { unsigned int i; float f; } v; v.i = u << 16; return v.f; }
__device__ __forceinline__ float bhi(unsigned int u) { union { unsigned int i; float f; } v; v.i = u & 0xffff0000u; return v.f; }
__device__ __forceinline__ float bf2f(unsigned short u) { union { unsigned int i; float f; } v; v.i = ((unsigned int)u) << 16; return v.f; }
__device__ __forceinline__ unsigned short f2bf(float f) {
    __hip_bfloat16 b = __float2bfloat16(f);
    unsigned short u; __builtin_memcpy(&u, &b, 2); return u;
}
__device__ __forceinline__ unsigned int pk2(float a, float b) {
    float2 t; t.x = a; t.y = b;
    __hip_bfloat162 h = __float22bfloat162_rn(t);
    unsigned int u; __builtin_memcpy(&u, &h, 4); return u;
}

// ------------- kernel 1: precompute (weights packed in-block) -------------
// 256 blocks x 4 waves, one row per wave.
__global__ __launch_bounds__(256) void precompute(
    const float* __restrict__ state,
    const float* __restrict__ Ws1, const float* __restrict__ bs1,
    const float* __restrict__ Ws2, const float* __restrict__ bs2,
    const float* __restrict__ Ws3, const float* __restrict__ bs3,
    const float* __restrict__ Wi1, const float* __restrict__ bi1,
    const float* __restrict__ Wi2, const float* __restrict__ bi2,
    const float* __restrict__ Wi3, const float* __restrict__ bi3,
    const float* __restrict__ phw, const float* __restrict__ Wc,
    const float* __restrict__ bc,  const float* __restrict__ aggr,
    float* __restrict__ ws, unsigned short* __restrict__ wsu) {
    const int tid = threadIdx.x;
    const int w = tid >> 6, t = tid & 63;
    const int i = blockIdx.x * 4 + w;

    __shared__ unsigned int wlds[PK_END];
    __shared__ float shh[4][32], shdh[4][32], sht1[4][64], sht2[4][64];
    __shared__ float shph[4];

    // ---- pack weights global -> LDS (coalesced float2 reads) ----
    {
        const float2* s1 = (const float2*)Ws1;          // 64x32 -> 1024 f2
        #pragma unroll
        for (int r = 0; r < 4; r++) { int e = tid + r * 256; int f = e >> 4, k2 = e & 15;
            float2 v = s1[e]; wlds[PK_W1 + k2 * 64 + f] = pk2(v.x, v.y); }
        const float2* s2 = (const float2*)Ws2;          // 64x64 -> 2048 f2
        #pragma unroll
        for (int r = 0; r < 8; r++) { int e = tid + r * 256; int f = e >> 5, k2 = e & 31;
            float2 v = s2[e]; wlds[PK_W2 + k2 * 64 + f] = pk2(v.x, v.y); }
        const float2* s3 = (const float2*)Ws3;          // 32x64 -> 1024 f2
        #pragma unroll
        for (int r = 0; r < 4; r++) { int e = tid + r * 256; int f = e >> 5, k2 = e & 31;
            float2 v = s3[e]; wlds[PK_W3 + k2 * 32 + f] = pk2(v.x, v.y); }
        const float2* si = (const float2*)Wi1;          // 64x128 -> 4096 f2
        #pragma unroll
        for (int r = 0; r < 16; r++) { int e = tid + r * 256; int f = e >> 6, c2 = e & 63;
            float2 v = si[e]; wlds[PK_WI1 + c2 * 64 + f] = pk2(v.x, v.y); }
        const float2* sc = (const float2*)Wc;           // 32x64 -> 1024 f2
        #pragma unroll
        for (int r = 0; r < 4; r++) { int e = tid + r * 256; int f = e >> 5, c2 = e & 31;
            float2 v = sc[e]; wlds[PK_WC + c2 * 32 + f] = pk2(v.x, v.y); }
    }
    // ---- block 0 publishes bf16 weights + biases for pair_kernel ----
    if (blockIdx.x == 0) {
        #pragma unroll
        for (int r = 0; r < 16; r++) { int e = tid + r * 256; wsu[U_W2B + e] = f2bf(Wi2[e]); }
        #pragma unroll
        for (int r = 0; r < 8; r++)  { int e = tid + r * 256; wsu[U_W3B + e] = f2bf(Wi3[e]); }
        if (tid < HDIM) ws[WS_BI2 + tid] = bi2[tid];
        if (tid < LDIM) { ws[WS_BI3 + tid] = bi3[tid]; ws[WS_BCB + tid] = bc[tid]; }
    }

    float sv = (t < 33) ? state[i * 33 + t] : 0.f;
    if (t < 32) shh[w][t] = sv;
    if (t == 32) shph[w] = sv;
    if (t == 33) ws[WS_AGG + i] = fast_sigmoid(aggr[i]);
    __syncthreads();

    // t1 = tanh(Ws1 @ h + bs1)
    {
        float s = bs1[t];
        const unsigned int* W = wlds + PK_W1;
        #pragma unroll
        for (int k2 = 0; k2 < 16; k2++) {
            unsigned int p = W[k2 * 64 + t];
            s = fmaf(blo(p), shh[w][2 * k2], s);
            s = fmaf(bhi(p), shh[w][2 * k2 + 1], s);
        }
        sht1[w][t] = fast_tanh(s);
    }
    __syncthreads();
    // t2 = tanh(Ws2 @ t1 + bs2)
    {
        float s = bs2[t];
        const unsigned int* W = wlds + PK_W2;
        #pragma unroll
        for (int k2 = 0; k2 < 32; k2++) {
            unsigned int p = W[k2 * 64 + t];
            s = fmaf(blo(p), sht1[w][2 * k2], s);
            s = fmaf(bhi(p), sht1[w][2 * k2 + 1], s);
        }
        sht2[w][t] = fast_tanh(s);
    }
    __syncthreads();
    // self = Ws3 @ t2 + bs3
    if (t < 32) {
        float s = bs3[t];
        const unsigned int* W = wlds + PK_W3;
        #pragma unroll
        for (int k2 = 0; k2 < 32; k2++) {
            unsigned int p = W[k2 * 32 + t];
            s = fmaf(blo(p), sht2[w][2 * k2], s);
            s = fmaf(bhi(p), sht2[w][2 * k2 + 1], s);
        }
        ws[WS_SELF + i * 32 + t] = s;
        shdh[w][t] = s;
    }
    __syncthreads();
    // a_i, b_j
    {
        float sa = 0.f, sb = bi1[t];
        const unsigned int* W = wlds + PK_WI1;
        #pragma unroll
        for (int k2 = 0; k2 < 16; k2++) {
            float h0 = shh[w][2 * k2], h1 = shh[w][2 * k2 + 1];
            float d0 = shdh[w][2 * k2], d1 = shdh[w][2 * k2 + 1];
            unsigned int wa  = W[k2 * 64 + t];
            unsigned int wb  = W[(16 + k2) * 64 + t];
            unsigned int wa2 = W[(32 + k2) * 64 + t];
            unsigned int wb2 = W[(48 + k2) * 64 + t];
            sa = fmaf(blo(wa), h0, sa);  sa = fmaf(bhi(wa), h1, sa);
            sb = fmaf(blo(wb), h0, sb);  sb = fmaf(bhi(wb), h1, sb);
            sa = fmaf(blo(wa2), d0, sa); sa = fmaf(bhi(wa2), d1, sa);
            sb = fmaf(blo(wb2), d0, sb); sb = fmaf(bhi(wb2), d1, sb);
        }
        ws[WS_AA + i * 64 + t] = sa;
        wsu[U_BJB + i * 64 + t] = f2bf(sb);
    }
    // ci, cj, phase tables, jtab
    if (t < 32) {
        float si = 0.f, sj = 0.f;
        const unsigned int* W = wlds + PK_WC;
        #pragma unroll
        for (int m2 = 0; m2 < 16; m2++) {
            float h0 = shh[w][2 * m2], h1 = shh[w][2 * m2 + 1];
            unsigned int wi = W[m2 * 32 + t];
            unsigned int wj = W[(16 + m2) * 32 + t];
            si = fmaf(blo(wi), h0, si); si = fmaf(bhi(wi), h1, si);
            sj = fmaf(blo(wj), h0, sj); sj = fmaf(bhi(wj), h1, sj);
        }
        ws[WS_CI + i * 32 + t] = si;
        float h = shh[w][t];
        wsu[U_HJB + i * 32 + t] = f2bf(h);
        float sc, cc;
        __sincosf(shph[w] * phw[t], &sc, &cc);
        uint2 jt; jt.x = pk2(h, sj); jt.y = pk2(cc, sc);
        *(uint2*)(wsu + U_JT + (i * 32 + t) * 4) = jt;
    }
}

// ------------- kernel 2: MFMA pairwise core (1 block per i) ---------------
__global__ __launch_bounds__(256, 4) void pair_kernel(
    const float* __restrict__ ws, const unsigned short* __restrict__ wsu,
    float* __restrict__ out) {
    const int i    = blockIdx.x;
    const int tid  = threadIdx.x;
    const int w    = tid >> 6;
    const int lane = tid & 63;
    const int q    = lane >> 4;
    const int m    = lane & 15;
    const int jw   = w * 16;
    const int sub  = lane & 3;

    __shared__ unsigned short W2ls[64 * 72];       // Wi2[n][k], stride 72
    __shared__ unsigned short x2ls[4 * 16 * 72];   // per-wave x2 tile
    __shared__ float aLS[64];                      // a_i
    __shared__ float red[4][32];

    // ---- setup ----
    if (tid < 64) aLS[tid] = ws[WS_AA + i * 64 + tid];
    { // Wi2 -> LDS, padded
        int row = tid >> 2, c = (tid & 3) * 16;
        const uint4* s2 = (const uint4*)(wsu + U_W2B + row * 64 + c);
        uint4 d0 = s2[0], d1 = s2[1];
        uint4* dd = (uint4*)(&W2ls[row * 72 + c]);
        dd[0] = d0; dd[1] = d1;
    }
    // per-lane h_i slice for fac distance
    float hi8[8];
    {
        uint4 hv4 = *(const uint4*)(wsu + U_HJB + i * 32 + sub * 8);
        unsigned int hd[4] = {hv4.x, hv4.y, hv4.z, hv4.w};
        #pragma unroll
        for (int e = 0; e < 4; e++) { hi8[2 * e] = blo(hd[e]); hi8[2 * e + 1] = bhi(hd[e]); }
    }
    float bi2v[4];
    #pragma unroll
    for (int nb = 0; nb < 4; nb++) bi2v[nb] = ws[WS_BI2 + nb * 16 + m];
    bf16x8 w3f[2][2];
    #pragma unroll
    for (int lb = 0; lb < 2; lb++)
        #pragma unroll
        for (int s = 0; s < 2; s++)
            w3f[lb][s] = *(const bf16x8*)(wsu + U_W3B + (lb * 16 + m) * 64 + s * 32 + q * 8);
    float hiv[2], cibv[2], picv[2], pisv[2], bi3v[2];
    #pragma unroll
    for (int lb = 0; lb < 2; lb++) {
        int l = lb * 16 + m;
        uint2 jti = *(const uint2*)(wsu + U_JT + (i * 32 + l) * 4);
        hiv[lb] = blo(jti.x);
        picv[lb] = blo(jti.y); pisv[lb] = bhi(jti.y);
        cibv[lb] = ws[WS_CI + i * 32 + l] + ws[WS_BCB + l];
        bi3v[lb] = ws[WS_BI3 + l];
    }
    const float aggi = ws[WS_AGG + i];

    // ---- per-lane streaming pointers + tile-0 prefetch ----
    const unsigned short* hp = wsu + U_HJB + (jw + (lane >> 2)) * 32 + sub * 8;
    const unsigned short* bp = wsu + U_BJB + (jw + m) * 64 + q * 8;
    const unsigned short* jp = wsu + U_JT + ((jw + q * 4) * 32 + m) * 4;

    uint4 hv = *(const uint4*)hp;
    uint4 bv0 = *(const uint4*)bp;
    uint4 bv1 = *(const uint4*)(bp + 32);
    uint2 jt0[4], jt1[4];
    #pragma unroll
    for (int r = 0; r < 4; r++) {
        jt0[r] = *(const uint2*)(jp + r * 128);
        jt1[r] = *(const uint2*)(jp + 64 + r * 128);
    }
    __syncthreads();   // W2ls + aLS ready

    float accC0 = 0.f, accC1 = 0.f;

    for (int T = 0; T < 16; T++) {
        const int jb = T * 64;
        // current-tile register copies
        uint4 hvc = hv, bv0c = bv0, bv1c = bv1;
        uint2 jc0[4], jc1[4];
        #pragma unroll
        for (int r = 0; r < 4; r++) { jc0[r] = jt0[r]; jc1[r] = jt1[r]; }
        // prefetch next tile
        if (T < 15) {
            hp += 2048; bp += 4096; jp += 8192;
            hv = *(const uint4*)hp;
            bv0 = *(const uint4*)bp;
            bv1 = *(const uint4*)(bp + 32);
            #pragma unroll
            for (int r = 0; r < 4; r++) {
                jt0[r] = *(const uint2*)(jp + r * 128);
                jt1[r] = *(const uint2*)(jp + 64 + r * 128);
            }
        }

        // 1) fac via shuffles (lane owns j = jb + jw + (lane>>2))
        float fv[4];
        {
            unsigned int hd[4] = {hvc.x, hvc.y, hvc.z, hvc.w};
            float s = 0.f;
            #pragma unroll
            for (int e = 0; e < 4; e++) {
                float d0 = hi8[2 * e]     - blo(hd[e]);
                float d1 = hi8[2 * e + 1] - bhi(hd[e]);
                s = fmaf(d0, d0, s); s = fmaf(d1, d1, s);
            }
            s += __shfl_xor(s, 1); s += __shfl_xor(s, 2);
            float facown = fminf(fast_rcp(sqrtf(s) + 1e-6f), 2.0f) * aggi;
            #pragma unroll
            for (int r = 0; r < 4; r++) fv[r] = __shfl(facown, (q * 4 + r) * 4);
        }

        // 2) x1 A-fragments: tanh(a_i[k] + b_j[k]) packed bf16
        bf16x8 afrag[2];
        {
            unsigned int bd[8] = {bv0c.x, bv0c.y, bv0c.z, bv0c.w, bv1c.x, bv1c.y, bv1c.z, bv1c.w};
            #pragma unroll
            for (int s = 0; s < 2; s++) {
                union { uint4 u4; bf16x8 v; } pkd;
                #pragma unroll
                for (int e = 0; e < 4; e++) {
                    const float* ab = &aLS[s * 32 + q * 8 + 2 * e];
                    float x0 = fast_tanh(ab[0] + blo(bd[s * 4 + e]));
                    float x1 = fast_tanh(ab[1] + bhi(bd[s * 4 + e]));
                    ((unsigned int*)&pkd.u4)[e] = pk2(x0, x1);
                }
                afrag[s] = pkd.v;
            }
        }

        // 3) stage A MFMAs: X2 = X1 @ Wi2^T
        f32x4 accA[4];
        #pragma unroll
        for (int nb = 0; nb < 4; nb++) {
            f32x4 acc = {0.f, 0.f, 0.f, 0.f};
            #pragma unroll
            for (int s = 0; s < 2; s++) {
                bf16x8 bfrag = *(const bf16x8*)(&W2ls[(nb * 16 + m) * 72 + s * 32 + q * 8]);
                acc = __builtin_amdgcn_mfma_f32_16x16x32_bf16(afrag[s], bfrag, acc, 0, 0, 0);
            }
            accA[nb] = acc;
        }
        // epilogue A: x2 = tanh(+bi2) -> per-wave LDS tile (C->A layout xform)
        {
            unsigned short* xw = &x2ls[w * 16 * 72];
            #pragma unroll
            for (int nb = 0; nb < 4; nb++) {
                #pragma unroll
                for (int r = 0; r < 4; r++)
                    xw[(q * 4 + r) * 72 + nb * 16 + m] = f2bf(fast_tanh(accA[nb][r] + bi2v[nb]));
            }
        }

        // 4) stage B MFMAs: K = X2 @ Wi3^T (same-wave LDS round-trip)
        f32x4 accB[2];
        {
            bf16x8 x2f[2];
            #pragma unroll
            for (int s = 0; s < 2; s++)
                x2f[s] = *(const bf16x8*)(&x2ls[(w * 16 + m) * 72 + s * 32 + q * 8]);
            #pragma unroll
            for (int lb = 0; lb < 2; lb++) {
                f32x4 acc = {0.f, 0.f, 0.f, 0.f};
                #pragma unroll
                for (int s = 0; s < 2; s++)
                    acc = __builtin_amdgcn_mfma_f32_16x16x32_bf16(x2f[s], w3f[lb][s], acc, 0, 0, 0);
                accB[lb] = acc;
            }
        }

        // 5) stage C combine + j-accumulate (from prefetched jtab regs)
        #pragma unroll
        for (int lb = 0; lb < 2; lb++) {
            float accl = 0.f;
            #pragma unroll
            for (int r = 0; r < 4; r++) {
                uint2 jv = (lb == 0) ? jc0[r] : jc1[r];
                float hj = blo(jv.x), cj = bhi(jv.x);
                float pjc = blo(jv.y), pjs = bhi(jv.y);
                float pf  = picv[lb] * pjc + pisv[lb] * pjs;
                float coh = fast_sigmoid(cibv[lb] + cj);
                float kv  = accB[lb][r] + bi3v[lb];
                float v   = fv[r] * kv - pf * coh * (hiv[lb] - hj);
                int j = jb + jw + q * 4 + r;
                if (j != i) accl += v;
            }
            if (lb == 0) accC0 += accl; else accC1 += accl;
        }
    }

    // ---- final reduction ----
    accC0 += __shfl_xor(accC0, 16); accC0 += __shfl_xor(accC0, 32);
    accC1 += __shfl_xor(accC1, 16); accC1 += __shfl_xor(accC1, 32);
    if (lane < 16) { red[w][m] = accC0; red[w][16 + m] = accC1; }
    __syncthreads();
    if (tid < 32) {
        float isum = red[0][tid] + red[1][tid] + red[2][tid] + red[3][tid];
        out[i * 33 + tid] = 0.5f * ws[WS_SELF + i * 32 + tid] + 0.3f * isum;
        red[0][tid] = fabsf(isum);
    }
    __syncthreads();
    if (tid == 0) {
        float s = 0.f;
        #pragma unroll
        for (int l = 0; l < 32; l++) s += red[0][l];
        out[i * 33 + 32] = 0.1f + 0.05f * s;
    }
}

extern "C" void kernel_launch(void* const* d_in, const int* in_sizes, int n_in,
                              void* d_out, int out_size, void* d_ws, size_t ws_size,
                              hipStream_t stream) {
    const float* state   = (const float*)d_in[0];
    const float* Ws1     = (const float*)d_in[1];
    const float* bs1     = (const float*)d_in[2];
    const float* Ws2     = (const float*)d_in[3];
    const float* bs2     = (const float*)d_in[4];
    const float* Ws3     = (const float*)d_in[5];
    const float* bs3     = (const float*)d_in[6];
    const float* Wi1     = (const float*)d_in[7];
    const float* bi1     = (const float*)d_in[8];
    const float* Wi2     = (const float*)d_in[9];
    const float* bi2     = (const float*)d_in[10];
    const float* Wi3     = (const float*)d_in[11];
    const float* bi3     = (const float*)d_in[12];
    const float* phase_w = (const float*)d_in[13];
    const float* Wc      = (const float*)d_in[14];
    const float* bc      = (const float*)d_in[15];
    const float* aggr    = (const float*)d_in[16];

    float* ws = (float*)d_ws;
    unsigned short* wsu = (unsigned short*)(ws + WS_FEND);
    float* out = (float*)d_out;

    precompute<<<256, 256, 0, stream>>>(state, Ws1, bs1, Ws2, bs2, Ws3, bs3,
                                        Wi1, bi1, Wi2, bi2, Wi3, bi3,
                                        phase_w, Wc, bc, aggr, ws, wsu);
    pair_kernel<<<NN, 256, 0, stream>>>(ws, wsu, out);
}

// Round 6
// 163.933 us; speedup vs baseline: 1.3027x; 1.2760x over previous
//
#include <hip/hip_runtime.h>
#include <hip/hip_bf16.h>
#include <math.h>

#define NN 1024
#define LDIM 32
#define HDIM 64

// ---------------- fp32 workspace layout (float offsets) ----------------
#define WS_SELF 0                        // N*L   self_term [i][l]
#define WS_AA   (WS_SELF + NN*LDIM)      // N*H   a_i [i][h]
#define WS_CI   (WS_AA   + NN*HDIM)      // N*L   ci [i][l]
#define WS_AGG  (WS_CI   + NN*LDIM)      // N     sigmoid(aggr)
#define WS_BI2  (WS_AGG  + NN)           // H
#define WS_BI3  (WS_BI2  + HDIM)         // L
#define WS_BCB  (WS_BI3  + LDIM)         // L     bc
#define WS_FEND (WS_BCB  + LDIM)

// ---------------- bf16(u16) region (short offsets from wsu) -------------
#define U_BJB  0                         // N*H   b_j [j][h]
#define U_HJB  (U_BJB + NN*HDIM)         // N*L   h   [j][l]
#define U_JT   (U_HJB + NN*LDIM)         // N*L*4 interleaved {h,cj | pc,ps}
#define U_W2B  (U_JT  + NN*LDIM*4)       // H*H   Wi2 [n][k]
#define U_W3B  (U_W2B + HDIM*HDIM)       // L*H   Wi3 [l][k]
#define U_END  (U_W3B + LDIM*HDIM)

// packed-pair transposed weight tables in precompute LDS (uint offsets)
#define PK_W1  0        // 16*64   Ws1
#define PK_W2  1024     // 32*64   Ws2
#define PK_W3  3072     // 32*32   Ws3
#define PK_WI1 4096     // 64*64   Wi1
#define PK_WC  8192     // 32*32   Wc
#define PK_END 9216     // 36 KB

typedef __attribute__((ext_vector_type(8))) short bf16x8;
typedef __attribute__((ext_vector_type(4))) float f32x4;

__device__ __forceinline__ float fast_rcp(float x) { return __builtin_amdgcn_rcpf(x); }
__device__ __forceinline__ float fast_tanh(float x) {
    float e = __builtin_amdgcn_exp2f(x * 2.88539008f);   // exp(2x)
    return 1.0f - 2.0f * fast_rcp(e + 1.0f);
}
__device__ __forceinline__ float fast_sigmoid(float x) {
    return fast_rcp(1.0f + __builtin_amdgcn_exp2f(x * -1.44269504f));
}
__device__ __forceinline__ float blo(unsigned int u) { union { unsigned int i; float f; } v; v.i = u << 16; return v.f; }
__device__ __forceinline__ float bhi(unsigned int u) { union { unsigned int i; float f; } v; v.i = u & 0xffff0000u; return v.f; }
__device__ __forceinline__ float bf2f(unsigned short u) { union { unsigned int i; float f; } v; v.i = ((unsigned int)u) << 16; return v.f; }
__device__ __forceinline__ unsigned short f2bf(float f) {
    __hip_bfloat16 b = __float2bfloat16(f);
    unsigned short u; __builtin_memcpy(&u, &b, 2); return u;
}
__device__ __forceinline__ unsigned int pk2(float a, float b) {
    float2 t; t.x = a; t.y = b;
    __hip_bfloat162 h = __float22bfloat162_rn(t);
    unsigned int u; __builtin_memcpy(&u, &h, 4); return u;
}

// ------------- kernel 1: precompute (weights packed in-block) -------------
// 256 blocks x 4 waves, one row per wave.
__global__ __launch_bounds__(256) void precompute(
    const float* __restrict__ state,
    const float* __restrict__ Ws1, const float* __restrict__ bs1,
    const float* __restrict__ Ws2, const float* __restrict__ bs2,
    const float* __restrict__ Ws3, const float* __restrict__ bs3,
    const float* __restrict__ Wi1, const float* __restrict__ bi1,
    const float* __restrict__ Wi2, const float* __restrict__ bi2,
    const float* __restrict__ Wi3, const float* __restrict__ bi3,
    const float* __restrict__ phw, const float* __restrict__ Wc,
    const float* __restrict__ bc,  const float* __restrict__ aggr,
    float* __restrict__ ws, unsigned short* __restrict__ wsu) {
    const int tid = threadIdx.x;
    const int w = tid >> 6, t = tid & 63;
    const int i = blockIdx.x * 4 + w;

    __shared__ unsigned int wlds[PK_END];
    __shared__ float shh[4][32], shdh[4][32], sht1[4][64], sht2[4][64];
    __shared__ float shph[4];

    // ---- pack weights global -> LDS (coalesced float2 reads) ----
    {
        const float2* s1 = (const float2*)Ws1;          // 64x32 -> 1024 f2
        #pragma unroll
        for (int r = 0; r < 4; r++) { int e = tid + r * 256; int f = e >> 4, k2 = e & 15;
            float2 v = s1[e]; wlds[PK_W1 + k2 * 64 + f] = pk2(v.x, v.y); }
        const float2* s2 = (const float2*)Ws2;          // 64x64 -> 2048 f2
        #pragma unroll
        for (int r = 0; r < 8; r++) { int e = tid + r * 256; int f = e >> 5, k2 = e & 31;
            float2 v = s2[e]; wlds[PK_W2 + k2 * 64 + f] = pk2(v.x, v.y); }
        const float2* s3 = (const float2*)Ws3;          // 32x64 -> 1024 f2
        #pragma unroll
        for (int r = 0; r < 4; r++) { int e = tid + r * 256; int f = e >> 5, k2 = e & 31;
            float2 v = s3[e]; wlds[PK_W3 + k2 * 32 + f] = pk2(v.x, v.y); }
        const float2* si = (const float2*)Wi1;          // 64x128 -> 4096 f2
        #pragma unroll
        for (int r = 0; r < 16; r++) { int e = tid + r * 256; int f = e >> 6, c2 = e & 63;
            float2 v = si[e]; wlds[PK_WI1 + c2 * 64 + f] = pk2(v.x, v.y); }
        const float2* sc = (const float2*)Wc;           // 32x64 -> 1024 f2
        #pragma unroll
        for (int r = 0; r < 4; r++) { int e = tid + r * 256; int f = e >> 5, c2 = e & 31;
            float2 v = sc[e]; wlds[PK_WC + c2 * 32 + f] = pk2(v.x, v.y); }
    }
    // ---- block 0 publishes bf16 weights + biases for pair_kernel ----
    if (blockIdx.x == 0) {
        #pragma unroll
        for (int r = 0; r < 16; r++) { int e = tid + r * 256; wsu[U_W2B + e] = f2bf(Wi2[e]); }
        #pragma unroll
        for (int r = 0; r < 8; r++)  { int e = tid + r * 256; wsu[U_W3B + e] = f2bf(Wi3[e]); }
        if (tid < HDIM) ws[WS_BI2 + tid] = bi2[tid];
        if (tid < LDIM) { ws[WS_BI3 + tid] = bi3[tid]; ws[WS_BCB + tid] = bc[tid]; }
    }

    float sv = (t < 33) ? state[i * 33 + t] : 0.f;
    if (t < 32) shh[w][t] = sv;
    if (t == 32) shph[w] = sv;
    if (t == 33) ws[WS_AGG + i] = fast_sigmoid(aggr[i]);
    __syncthreads();

    // t1 = tanh(Ws1 @ h + bs1)
    {
        float s = bs1[t];
        const unsigned int* W = wlds + PK_W1;
        #pragma unroll
        for (int k2 = 0; k2 < 16; k2++) {
            unsigned int p = W[k2 * 64 + t];
            s = fmaf(blo(p), shh[w][2 * k2], s);
            s = fmaf(bhi(p), shh[w][2 * k2 + 1], s);
        }
        sht1[w][t] = fast_tanh(s);
    }
    __syncthreads();
    // t2 = tanh(Ws2 @ t1 + bs2)
    {
        float s = bs2[t];
        const unsigned int* W = wlds + PK_W2;
        #pragma unroll
        for (int k2 = 0; k2 < 32; k2++) {
            unsigned int p = W[k2 * 64 + t];
            s = fmaf(blo(p), sht1[w][2 * k2], s);
            s = fmaf(bhi(p), sht1[w][2 * k2 + 1], s);
        }
        sht2[w][t] = fast_tanh(s);
    }
    __syncthreads();
    // self = Ws3 @ t2 + bs3
    if (t < 32) {
        float s = bs3[t];
        const unsigned int* W = wlds + PK_W3;
        #pragma unroll
        for (int k2 = 0; k2 < 32; k2++) {
            unsigned int p = W[k2 * 32 + t];
            s = fmaf(blo(p), sht2[w][2 * k2], s);
            s = fmaf(bhi(p), sht2[w][2 * k2 + 1], s);
        }
        ws[WS_SELF + i * 32 + t] = s;
        shdh[w][t] = s;
    }
    __syncthreads();
    // a_i, b_j
    {
        float sa = 0.f, sb = bi1[t];
        const unsigned int* W = wlds + PK_WI1;
        #pragma unroll
        for (int k2 = 0; k2 < 16; k2++) {
            float h0 = shh[w][2 * k2], h1 = shh[w][2 * k2 + 1];
            float d0 = shdh[w][2 * k2], d1 = shdh[w][2 * k2 + 1];
            unsigned int wa  = W[k2 * 64 + t];
            unsigned int wb  = W[(16 + k2) * 64 + t];
            unsigned int wa2 = W[(32 + k2) * 64 + t];
            unsigned int wb2 = W[(48 + k2) * 64 + t];
            sa = fmaf(blo(wa), h0, sa);  sa = fmaf(bhi(wa), h1, sa);
            sb = fmaf(blo(wb), h0, sb);  sb = fmaf(bhi(wb), h1, sb);
            sa = fmaf(blo(wa2), d0, sa); sa = fmaf(bhi(wa2), d1, sa);
            sb = fmaf(blo(wb2), d0, sb); sb = fmaf(bhi(wb2), d1, sb);
        }
        ws[WS_AA + i * 64 + t] = sa;
        wsu[U_BJB + i * 64 + t] = f2bf(sb);
    }
    // ci, cj, phase tables, jtab
    if (t < 32) {
        float si = 0.f, sj = 0.f;
        const unsigned int* W = wlds + PK_WC;
        #pragma unroll
        for (int m2 = 0; m2 < 16; m2++) {
            float h0 = shh[w][2 * m2], h1 = shh[w][2 * m2 + 1];
            unsigned int wi = W[m2 * 32 + t];
            unsigned int wj = W[(16 + m2) * 32 + t];
            si = fmaf(blo(wi), h0, si); si = fmaf(bhi(wi), h1, si);
            sj = fmaf(blo(wj), h0, sj); sj = fmaf(bhi(wj), h1, sj);
        }
        ws[WS_CI + i * 32 + t] = si;
        float h = shh[w][t];
        wsu[U_HJB + i * 32 + t] = f2bf(h);
        float sc, cc;
        __sincosf(shph[w] * phw[t], &sc, &cc);
        uint2 jt; jt.x = pk2(h, sj); jt.y = pk2(cc, sc);
        *(uint2*)(wsu + U_JT + (i * 32 + t) * 4) = jt;
    }
}

// ------------- kernel 2: MFMA pairwise core (1 block per i) ---------------
// NOTE: no min-waves bound — round 5's (256,4) clamped VGPRs to 64 and
// spilled the prefetch state in-loop (WRITE_SIZE 54 MB, FETCH 317 MB).
__global__ __launch_bounds__(256) void pair_kernel(
    const float* __restrict__ ws, const unsigned short* __restrict__ wsu,
    float* __restrict__ out) {
    const int i    = blockIdx.x;
    const int tid  = threadIdx.x;
    const int w    = tid >> 6;
    const int lane = tid & 63;
    const int q    = lane >> 4;
    const int m    = lane & 15;
    const int jw   = w * 16;
    const int sub  = lane & 3;

    __shared__ unsigned short W2ls[64 * 72];       // Wi2[n][k], stride 72
    __shared__ unsigned short W3ls[32 * 72];       // Wi3[l][k], stride 72
    __shared__ unsigned short x2ls[4 * 16 * 72];   // per-wave x2 tile
    __shared__ float aLS[64];                      // a_i
    __shared__ float red[4][32];

    // ---- setup ----
    if (tid < 64) aLS[tid] = ws[WS_AA + i * 64 + tid];
    { // Wi2 -> LDS, padded
        int row = tid >> 2, c = (tid & 3) * 16;
        const uint4* s2 = (const uint4*)(wsu + U_W2B + row * 64 + c);
        uint4 d0 = s2[0], d1 = s2[1];
        uint4* dd = (uint4*)(&W2ls[row * 72 + c]);
        dd[0] = d0; dd[1] = d1;
        if (row < 32) {   // Wi3 -> LDS
            const uint4* s3 = (const uint4*)(wsu + U_W3B + row * 64 + c);
            uint4 e0 = s3[0], e1 = s3[1];
            uint4* d3 = (uint4*)(&W3ls[row * 72 + c]);
            d3[0] = e0; d3[1] = e1;
        }
    }
    // per-lane h_i slice for fac distance
    float hi8[8];
    {
        uint4 hv4 = *(const uint4*)(wsu + U_HJB + i * 32 + sub * 8);
        unsigned int hd[4] = {hv4.x, hv4.y, hv4.z, hv4.w};
        #pragma unroll
        for (int e = 0; e < 4; e++) { hi8[2 * e] = blo(hd[e]); hi8[2 * e + 1] = bhi(hd[e]); }
    }
    float bi2v[4];
    #pragma unroll
    for (int nb = 0; nb < 4; nb++) bi2v[nb] = ws[WS_BI2 + nb * 16 + m];
    float hiv[2], cibv[2], picv[2], pisv[2], bi3v[2];
    #pragma unroll
    for (int lb = 0; lb < 2; lb++) {
        int l = lb * 16 + m;
        uint2 jti = *(const uint2*)(wsu + U_JT + (i * 32 + l) * 4);
        hiv[lb] = blo(jti.x);
        picv[lb] = blo(jti.y); pisv[lb] = bhi(jti.y);
        cibv[lb] = ws[WS_CI + i * 32 + l] + ws[WS_BCB + l];
        bi3v[lb] = ws[WS_BI3 + l];
    }
    const float aggi = ws[WS_AGG + i];

    // ---- per-lane streaming pointers + tile-0 prefetch ----
    const unsigned short* hp = wsu + U_HJB + (jw + (lane >> 2)) * 32 + sub * 8;
    const unsigned short* bp = wsu + U_BJB + (jw + m) * 64 + q * 8;
    const unsigned short* jp = wsu + U_JT + ((jw + q * 4) * 32 + m) * 4;

    uint4 hv = *(const uint4*)hp;
    uint4 bv0 = *(const uint4*)bp;
    uint4 bv1 = *(const uint4*)(bp + 32);
    uint2 jt0[4], jt1[4];
    #pragma unroll
    for (int r = 0; r < 4; r++) {
        jt0[r] = *(const uint2*)(jp + r * 128);
        jt1[r] = *(const uint2*)(jp + 64 + r * 128);
    }
    __syncthreads();   // W2ls/W3ls/aLS ready

    float accC0 = 0.f, accC1 = 0.f;

    for (int T = 0; T < 16; T++) {
        const int jb = T * 64;
        // current-tile register copies
        uint4 hvc = hv, bv0c = bv0, bv1c = bv1;
        uint2 jc0[4], jc1[4];
        #pragma unroll
        for (int r = 0; r < 4; r++) { jc0[r] = jt0[r]; jc1[r] = jt1[r]; }
        // prefetch next tile
        if (T < 15) {
            hp += 2048; bp += 4096; jp += 8192;
            hv = *(const uint4*)hp;
            bv0 = *(const uint4*)bp;
            bv1 = *(const uint4*)(bp + 32);
            #pragma unroll
            for (int r = 0; r < 4; r++) {
                jt0[r] = *(const uint2*)(jp + r * 128);
                jt1[r] = *(const uint2*)(jp + 64 + r * 128);
            }
        }

        // 1) fac via shuffles (lane owns j = jb + jw + (lane>>2))
        float fv[4];
        {
            unsigned int hd[4] = {hvc.x, hvc.y, hvc.z, hvc.w};
            float s = 0.f;
            #pragma unroll
            for (int e = 0; e < 4; e++) {
                float d0 = hi8[2 * e]     - blo(hd[e]);
                float d1 = hi8[2 * e + 1] - bhi(hd[e]);
                s = fmaf(d0, d0, s); s = fmaf(d1, d1, s);
            }
            s += __shfl_xor(s, 1); s += __shfl_xor(s, 2);
            float facown = fminf(fast_rcp(sqrtf(s) + 1e-6f), 2.0f) * aggi;
            #pragma unroll
            for (int r = 0; r < 4; r++) fv[r] = __shfl(facown, (q * 4 + r) * 4);
        }

        // 2) x1 A-fragments: tanh(a_i[k] + b_j[k]) packed bf16
        bf16x8 afrag[2];
        {
            unsigned int bd[8] = {bv0c.x, bv0c.y, bv0c.z, bv0c.w, bv1c.x, bv1c.y, bv1c.z, bv1c.w};
            #pragma unroll
            for (int s = 0; s < 2; s++) {
                union { uint4 u4; bf16x8 v; } pkd;
                #pragma unroll
                for (int e = 0; e < 4; e++) {
                    const float* ab = &aLS[s * 32 + q * 8 + 2 * e];
                    float x0 = fast_tanh(ab[0] + blo(bd[s * 4 + e]));
                    float x1 = fast_tanh(ab[1] + bhi(bd[s * 4 + e]));
                    ((unsigned int*)&pkd.u4)[e] = pk2(x0, x1);
                }
                afrag[s] = pkd.v;
            }
        }

        // 3) stage A MFMAs: X2 = X1 @ Wi2^T
        f32x4 accA[4];
        #pragma unroll
        for (int nb = 0; nb < 4; nb++) {
            f32x4 acc = {0.f, 0.f, 0.f, 0.f};
            #pragma unroll
            for (int s = 0; s < 2; s++) {
                bf16x8 bfrag = *(const bf16x8*)(&W2ls[(nb * 16 + m) * 72 + s * 32 + q * 8]);
                acc = __builtin_amdgcn_mfma_f32_16x16x32_bf16(afrag[s], bfrag, acc, 0, 0, 0);
            }
            accA[nb] = acc;
        }
        // epilogue A: x2 = tanh(+bi2) -> per-wave LDS tile (C->A layout xform)
        {
            unsigned short* xw = &x2ls[w * 16 * 72];
            #pragma unroll
            for (int nb = 0; nb < 4; nb++) {
                #pragma unroll
                for (int r = 0; r < 4; r++)
                    xw[(q * 4 + r) * 72 + nb * 16 + m] = f2bf(fast_tanh(accA[nb][r] + bi2v[nb]));
            }
        }

        // 4) stage B MFMAs: K = X2 @ Wi3^T (same-wave LDS round-trip)
        f32x4 accB[2];
        {
            bf16x8 x2f[2];
            #pragma unroll
            for (int s = 0; s < 2; s++)
                x2f[s] = *(const bf16x8*)(&x2ls[(w * 16 + m) * 72 + s * 32 + q * 8]);
            #pragma unroll
            for (int lb = 0; lb < 2; lb++) {
                f32x4 acc = {0.f, 0.f, 0.f, 0.f};
                #pragma unroll
                for (int s = 0; s < 2; s++) {
                    bf16x8 w3frag = *(const bf16x8*)(&W3ls[(lb * 16 + m) * 72 + s * 32 + q * 8]);
                    acc = __builtin_amdgcn_mfma_f32_16x16x32_bf16(x2f[s], w3frag, acc, 0, 0, 0);
                }
                accB[lb] = acc;
            }
        }

        // 5) stage C combine + j-accumulate (from prefetched jtab regs)
        #pragma unroll
        for (int lb = 0; lb < 2; lb++) {
            float accl = 0.f;
            #pragma unroll
            for (int r = 0; r < 4; r++) {
                uint2 jv = (lb == 0) ? jc0[r] : jc1[r];
                float hj = blo(jv.x), cj = bhi(jv.x);
                float pjc = blo(jv.y), pjs = bhi(jv.y);
                float pf  = picv[lb] * pjc + pisv[lb] * pjs;
                float coh = fast_sigmoid(cibv[lb] + cj);
                float kv  = accB[lb][r] + bi3v[lb];
                float v   = fv[r] * kv - pf * coh * (hiv[lb] - hj);
                int j = jb + jw + q * 4 + r;
                if (j != i) accl += v;
            }
            if (lb == 0) accC0 += accl; else accC1 += accl;
        }
    }

    // ---- final reduction ----
    accC0 += __shfl_xor(accC0, 16); accC0 += __shfl_xor(accC0, 32);
    accC1 += __shfl_xor(accC1, 16); accC1 += __shfl_xor(accC1, 32);
    if (lane < 16) { red[w][m] = accC0; red[w][16 + m] = accC1; }
    __syncthreads();
    if (tid < 32) {
        float isum = red[0][tid] + red[1][tid] + red[2][tid] + red[3][tid];
        out[i * 33 + tid] = 0.5f * ws[WS_SELF + i * 32 + tid] + 0.3f * isum;
        red[0][tid] = fabsf(isum);
    }
    __syncthreads();
    if (tid == 0) {
        float s = 0.f;
        #pragma unroll
        for (int l = 0; l < 32; l++) s += red[0][l];
        out[i * 33 + 32] = 0.1f + 0.05f * s;
    }
}

extern "C" void kernel_launch(void* const* d_in, const int* in_sizes, int n_in,
                              void* d_out, int out_size, void* d_ws, size_t ws_size,
                              hipStream_t stream) {
    const float* state   = (const float*)d_in[0];
    const float* Ws1     = (const float*)d_in[1];
    const float* bs1     = (const float*)d_in[2];
    const float* Ws2     = (const float*)d_in[3];
    const float* bs2     = (const float*)d_in[4];
    const float* Ws3     = (const float*)d_in[5];
    const float* bs3     = (const float*)d_in[6];
    const float* Wi1     = (const float*)d_in[7];
    const float* bi1     = (const float*)d_in[8];
    const float* Wi2     = (const float*)d_in[9];
    const float* bi2     = (const float*)d_in[10];
    const float* Wi3     = (const float*)d_in[11];
    const float* bi3     = (const float*)d_in[12];
    const float* phase_w = (const float*)d_in[13];
    const float* Wc      = (const float*)d_in[14];
    const float* bc      = (const float*)d_in[15];
    const float* aggr    = (const float*)d_in[16];

    float* ws = (float*)d_ws;
    unsigned short* wsu = (unsigned short*)(ws + WS_FEND);
    float* out = (float*)d_out;

    precompute<<<256, 256, 0, stream>>>(state, Ws1, bs1, Ws2, bs2, Ws3, bs3,
                                        Wi1, bi1, Wi2, bi2, Wi3, bi3,
                                        phase_w, Wc, bc, aggr, ws, wsu);
    pair_kernel<<<NN, 256, 0, stream>>>(ws, wsu, out);
}

// Round 7
// 154.557 us; speedup vs baseline: 1.3817x; 1.0607x over previous
//
#include <hip/hip_runtime.h>
#include <hip/hip_bf16.h>
#include <math.h>

#define NN 1024
#define LDIM 32
#define HDIM 64

// ---------------- fp32 workspace layout (float offsets) ----------------
#define WS_SELF 0                        // N*L   self_term [i][l]
#define WS_AA   (WS_SELF + NN*LDIM)      // N*H   a_i [i][h]
#define WS_CI   (WS_AA   + NN*HDIM)      // N*L   ci [i][l]
#define WS_AGG  (WS_CI   + NN*LDIM)      // N     sigmoid(aggr)
#define WS_BI2  (WS_AGG  + NN)           // H
#define WS_BI3  (WS_BI2  + HDIM)         // L
#define WS_BCB  (WS_BI3  + LDIM)         // L     bc
#define WS_FEND (WS_BCB  + LDIM)

// ---------------- bf16(u16) region (short offsets from wsu) -------------
#define U_BJB  0                         // N*H   b_j [j][h]
#define U_HJB  (U_BJB + NN*HDIM)         // N*L   h   [j][l]
#define U_JT   (U_HJB + NN*LDIM)         // N*L*4 interleaved {h,cj | pc,ps}
#define U_W2B  (U_JT  + NN*LDIM*4)       // H*H   Wi2 [n][k]
#define U_W3B  (U_W2B + HDIM*HDIM)       // L*H   Wi3 [l][k]
#define U_END  (U_W3B + LDIM*HDIM)

// packed-pair transposed weight tables in precompute LDS (uint offsets)
#define PK_W1  0        // 16*64   Ws1
#define PK_W2  1024     // 32*64   Ws2
#define PK_W3  3072     // 32*32   Ws3
#define PK_WI1 4096     // 64*64   Wi1
#define PK_WC  8192     // 32*32   Wc
#define PK_END 9216     // 36 KB

typedef __attribute__((ext_vector_type(8))) short bf16x8;
typedef __attribute__((ext_vector_type(4))) float f32x4;

__device__ __forceinline__ float fast_rcp(float x) { return __builtin_amdgcn_rcpf(x); }
__device__ __forceinline__ float fast_tanh(float x) {
    float e = __builtin_amdgcn_exp2f(x * 2.88539008f);   // exp(2x)
    return 1.0f - 2.0f * fast_rcp(e + 1.0f);
}
__device__ __forceinline__ float fast_sigmoid(float x) {
    return fast_rcp(1.0f + __builtin_amdgcn_exp2f(x * -1.44269504f));
}
__device__ __forceinline__ float blo(unsigned int u) { union { unsigned int i; float f; } v; v.i = u << 16; return v.f; }
__device__ __forceinline__ float bhi(unsigned int u) { union { unsigned int i; float f; } v; v.i = u & 0xffff0000u; return v.f; }
__device__ __forceinline__ float bf2f(unsigned short u) { union { unsigned int i; float f; } v; v.i = ((unsigned int)u) << 16; return v.f; }
__device__ __forceinline__ unsigned short f2bf(float f) {
    __hip_bfloat16 b = __float2bfloat16(f);
    unsigned short u; __builtin_memcpy(&u, &b, 2); return u;
}
__device__ __forceinline__ unsigned int pk2(float a, float b) {
    float2 t; t.x = a; t.y = b;
    __hip_bfloat162 h = __float22bfloat162_rn(t);
    unsigned int u; __builtin_memcpy(&u, &h, 4); return u;
}

// ------------- kernel 1: precompute (weights packed in-block) -------------
__global__ __launch_bounds__(256) void precompute(
    const float* __restrict__ state,
    const float* __restrict__ Ws1, const float* __restrict__ bs1,
    const float* __restrict__ Ws2, const float* __restrict__ bs2,
    const float* __restrict__ Ws3, const float* __restrict__ bs3,
    const float* __restrict__ Wi1, const float* __restrict__ bi1,
    const float* __restrict__ Wi2, const float* __restrict__ bi2,
    const float* __restrict__ Wi3, const float* __restrict__ bi3,
    const float* __restrict__ phw, const float* __restrict__ Wc,
    const float* __restrict__ bc,  const float* __restrict__ aggr,
    float* __restrict__ ws, unsigned short* __restrict__ wsu) {
    const int tid = threadIdx.x;
    const int w = tid >> 6, t = tid & 63;
    const int i = blockIdx.x * 4 + w;

    __shared__ unsigned int wlds[PK_END];
    __shared__ float shh[4][32], shdh[4][32], sht1[4][64], sht2[4][64];
    __shared__ float shph[4];

    {
        const float2* s1 = (const float2*)Ws1;
        #pragma unroll
        for (int r = 0; r < 4; r++) { int e = tid + r * 256; int f = e >> 4, k2 = e & 15;
            float2 v = s1[e]; wlds[PK_W1 + k2 * 64 + f] = pk2(v.x, v.y); }
        const float2* s2 = (const float2*)Ws2;
        #pragma unroll
        for (int r = 0; r < 8; r++) { int e = tid + r * 256; int f = e >> 5, k2 = e & 31;
            float2 v = s2[e]; wlds[PK_W2 + k2 * 64 + f] = pk2(v.x, v.y); }
        const float2* s3 = (const float2*)Ws3;
        #pragma unroll
        for (int r = 0; r < 4; r++) { int e = tid + r * 256; int f = e >> 5, k2 = e & 31;
            float2 v = s3[e]; wlds[PK_W3 + k2 * 32 + f] = pk2(v.x, v.y); }
        const float2* si = (const float2*)Wi1;
        #pragma unroll
        for (int r = 0; r < 16; r++) { int e = tid + r * 256; int f = e >> 6, c2 = e & 63;
            float2 v = si[e]; wlds[PK_WI1 + c2 * 64 + f] = pk2(v.x, v.y); }
        const float2* sc = (const float2*)Wc;
        #pragma unroll
        for (int r = 0; r < 4; r++) { int e = tid + r * 256; int f = e >> 5, c2 = e & 31;
            float2 v = sc[e]; wlds[PK_WC + c2 * 32 + f] = pk2(v.x, v.y); }
    }
    if (blockIdx.x == 0) {
        #pragma unroll
        for (int r = 0; r < 16; r++) { int e = tid + r * 256; wsu[U_W2B + e] = f2bf(Wi2[e]); }
        #pragma unroll
        for (int r = 0; r < 8; r++)  { int e = tid + r * 256; wsu[U_W3B + e] = f2bf(Wi3[e]); }
        if (tid < HDIM) ws[WS_BI2 + tid] = bi2[tid];
        if (tid < LDIM) { ws[WS_BI3 + tid] = bi3[tid]; ws[WS_BCB + tid] = bc[tid]; }
    }

    float sv = (t < 33) ? state[i * 33 + t] : 0.f;
    if (t < 32) shh[w][t] = sv;
    if (t == 32) shph[w] = sv;
    if (t == 33) ws[WS_AGG + i] = fast_sigmoid(aggr[i]);
    __syncthreads();

    {
        float s = bs1[t];
        const unsigned int* W = wlds + PK_W1;
        #pragma unroll
        for (int k2 = 0; k2 < 16; k2++) {
            unsigned int p = W[k2 * 64 + t];
            s = fmaf(blo(p), shh[w][2 * k2], s);
            s = fmaf(bhi(p), shh[w][2 * k2 + 1], s);
        }
        sht1[w][t] = fast_tanh(s);
    }
    __syncthreads();
    {
        float s = bs2[t];
        const unsigned int* W = wlds + PK_W2;
        #pragma unroll
        for (int k2 = 0; k2 < 32; k2++) {
            unsigned int p = W[k2 * 64 + t];
            s = fmaf(blo(p), sht1[w][2 * k2], s);
            s = fmaf(bhi(p), sht1[w][2 * k2 + 1], s);
        }
        sht2[w][t] = fast_tanh(s);
    }
    __syncthreads();
    if (t < 32) {
        float s = bs3[t];
        const unsigned int* W = wlds + PK_W3;
        #pragma unroll
        for (int k2 = 0; k2 < 32; k2++) {
            unsigned int p = W[k2 * 32 + t];
            s = fmaf(blo(p), sht2[w][2 * k2], s);
            s = fmaf(bhi(p), sht2[w][2 * k2 + 1], s);
        }
        ws[WS_SELF + i * 32 + t] = s;
        shdh[w][t] = s;
    }
    __syncthreads();
    {
        float sa = 0.f, sb = bi1[t];
        const unsigned int* W = wlds + PK_WI1;
        #pragma unroll
        for (int k2 = 0; k2 < 16; k2++) {
            float h0 = shh[w][2 * k2], h1 = shh[w][2 * k2 + 1];
            float d0 = shdh[w][2 * k2], d1 = shdh[w][2 * k2 + 1];
            unsigned int wa  = W[k2 * 64 + t];
            unsigned int wb  = W[(16 + k2) * 64 + t];
            unsigned int wa2 = W[(32 + k2) * 64 + t];
            unsigned int wb2 = W[(48 + k2) * 64 + t];
            sa = fmaf(blo(wa), h0, sa);  sa = fmaf(bhi(wa), h1, sa);
            sb = fmaf(blo(wb), h0, sb);  sb = fmaf(bhi(wb), h1, sb);
            sa = fmaf(blo(wa2), d0, sa); sa = fmaf(bhi(wa2), d1, sa);
            sb = fmaf(blo(wb2), d0, sb); sb = fmaf(bhi(wb2), d1, sb);
        }
        ws[WS_AA + i * 64 + t] = sa;
        wsu[U_BJB + i * 64 + t] = f2bf(sb);
    }
    if (t < 32) {
        float si = 0.f, sj = 0.f;
        const unsigned int* W = wlds + PK_WC;
        #pragma unroll
        for (int m2 = 0; m2 < 16; m2++) {
            float h0 = shh[w][2 * m2], h1 = shh[w][2 * m2 + 1];
            unsigned int wi = W[m2 * 32 + t];
            unsigned int wj = W[(16 + m2) * 32 + t];
            si = fmaf(blo(wi), h0, si); si = fmaf(bhi(wi), h1, si);
            sj = fmaf(blo(wj), h0, sj); sj = fmaf(bhi(wj), h1, sj);
        }
        ws[WS_CI + i * 32 + t] = si;
        float h = shh[w][t];
        wsu[U_HJB + i * 32 + t] = f2bf(h);
        float sc, cc;
        __sincosf(shph[w] * phw[t], &sc, &cc);
        uint2 jt; jt.x = pk2(h, sj); jt.y = pk2(cc, sc);
        *(uint2*)(wsu + U_JT + (i * 32 + t) * 4) = jt;
    }
}

// ------------- kernel 2: MFMA pairwise core (1 block per i) ---------------
// Stage A computes X2^T = Wi2 * X1^T (operand swap: identical frag layouts)
// so the epilogue writes are r-contiguous (ds_write_b64) and fac is a
// single per-lane column scale. Stage B accumulates Sum_j fac_j*k_jl
// directly in a persistent MFMA C accumulator (bias via Sum fac * bi3 at
// the end). Stage C only accumulates the quantum term, factored as
// U=Sum coh*diff*pjc, V=Sum coh*diff*pjs; pf applied once at the end.
__global__ __launch_bounds__(256) void pair_kernel(
    const float* __restrict__ ws, const unsigned short* __restrict__ wsu,
    float* __restrict__ out) {
    const int i    = blockIdx.x;
    const int tid  = threadIdx.x;
    const int w    = tid >> 6;
    const int lane = tid & 63;
    const int q    = lane >> 4;
    const int m    = lane & 15;
    const int jw   = w * 16;
    const int sub  = lane & 3;

    __shared__ unsigned short W2ls[64 * 72];
    __shared__ unsigned short W3ls[32 * 72];
    __shared__ unsigned short x2ls[4 * 16 * 72];
    __shared__ float aLS[64];
    __shared__ float redT[4][32], redU[4][32], redV[4][32];
    __shared__ float sfw[4];

    // ---- setup ----
    if (tid < 64) aLS[tid] = ws[WS_AA + i * 64 + tid];
    {
        int row = tid >> 2, c = (tid & 3) * 16;
        const uint4* s2 = (const uint4*)(wsu + U_W2B + row * 64 + c);
        uint4 d0 = s2[0], d1 = s2[1];
        uint4* dd = (uint4*)(&W2ls[row * 72 + c]);
        dd[0] = d0; dd[1] = d1;
        if (row < 32) {
            const uint4* s3 = (const uint4*)(wsu + U_W3B + row * 64 + c);
            uint4 e0 = s3[0], e1 = s3[1];
            uint4* d3 = (uint4*)(&W3ls[row * 72 + c]);
            d3[0] = e0; d3[1] = e1;
        }
    }
    float hi8[8];
    {
        uint4 hv4 = *(const uint4*)(wsu + U_HJB + i * 32 + sub * 8);
        unsigned int hd[4] = {hv4.x, hv4.y, hv4.z, hv4.w};
        #pragma unroll
        for (int e = 0; e < 4; e++) { hi8[2 * e] = blo(hd[e]); hi8[2 * e + 1] = bhi(hd[e]); }
    }
    f32x4 b2q[4];              // bias slice for MFMA C-init: bi2[nb*16+q*4+r]
    #pragma unroll
    for (int nb = 0; nb < 4; nb++) {
        float4 bv = *(const float4*)(ws + WS_BI2 + nb * 16 + q * 4);
        b2q[nb][0] = bv.x; b2q[nb][1] = bv.y; b2q[nb][2] = bv.z; b2q[nb][3] = bv.w;
    }
    float hiv[2], cibv[2];
    #pragma unroll
    for (int lb = 0; lb < 2; lb++) {
        int l = lb * 16 + m;
        hiv[lb]  = bf2f(wsu[U_HJB + i * 32 + l]);
        cibv[lb] = ws[WS_CI + i * 32 + l] + ws[WS_BCB + l];
    }
    const float aggi = ws[WS_AGG + i];
    const float sub0 = (sub == 0) ? 1.0f : 0.0f;

    // ---- streaming pointers + tile-0 prefetch ----
    const unsigned short* hp = wsu + U_HJB + (jw + (lane >> 2)) * 32 + sub * 8;
    const unsigned short* bp = wsu + U_BJB + (jw + m) * 64 + q * 8;
    const unsigned short* jp = wsu + U_JT + ((jw + q * 4) * 32 + m) * 4;

    uint4 hvA = *(const uint4*)hp;
    uint4 b0A = *(const uint4*)bp;
    uint4 b1A = *(const uint4*)(bp + 32);
    uint4 hvB, b0B, b1B;
    __syncthreads();

    // persistent accumulators
    f32x4 accK[2];
    #pragma unroll
    for (int lb = 0; lb < 2; lb++) { accK[lb][0]=0.f; accK[lb][1]=0.f; accK[lb][2]=0.f; accK[lb][3]=0.f; }
    float aU[2] = {0.f, 0.f}, aV[2] = {0.f, 0.f};
    float sumfac = 0.f;

    unsigned short* xw = &x2ls[w * 16 * 72];

    auto body = [&](int T, uint4 hvc, uint4 b0c, uint4 b1c,
                    uint4& hvn, uint4& b0n, uint4& b1n) {
        // prefetch next tile's h/b (consumed early next body)
        hp += 2048; bp += 4096;
        hvn = *(const uint4*)hp;
        b0n = *(const uint4*)bp;
        b1n = *(const uint4*)(bp + 32);
        // jt loads for CURRENT tile (consumed at body end ~800cy later)
        uint2 jt[8];
        #pragma unroll
        for (int r = 0; r < 4; r++) {
            jt[r]     = *(const uint2*)(jp + r * 128);
            jt[4 + r] = *(const uint2*)(jp + 64 + r * 128);
        }
        jp += 8192;

        // 1) fac (lane owns j = T*64 + jw + (lane>>2)); zeroed at j==i
        float facm;
        {
            unsigned int hd[4] = {hvc.x, hvc.y, hvc.z, hvc.w};
            float s = 0.f;
            #pragma unroll
            for (int e = 0; e < 4; e++) {
                float d0 = hi8[2 * e]     - blo(hd[e]);
                float d1 = hi8[2 * e + 1] - bhi(hd[e]);
                s = fmaf(d0, d0, s); s = fmaf(d1, d1, s);
            }
            s += __shfl_xor(s, 1); s += __shfl_xor(s, 2);
            int jj = T * 64 + jw + (lane >> 2);
            float facown = fminf(fast_rcp(sqrtf(s) + 1e-6f), 2.0f) * aggi;
            facown = (jj == i) ? 0.0f : facown;
            sumfac = fmaf(sub0, facown, sumfac);
            facm = __shfl(facown, 4 * m);    // fac for this lane's column j
        }

        // 2) x1 B-fragments: tanh(a_i[k] + b_j[k]) packed bf16 (j = col m)
        bf16x8 afr[2];
        {
            unsigned int bd[8] = {b0c.x, b0c.y, b0c.z, b0c.w, b1c.x, b1c.y, b1c.z, b1c.w};
            #pragma unroll
            for (int s = 0; s < 2; s++) {
                union { uint4 u4; bf16x8 v; } pkd;
                #pragma unroll
                for (int e = 0; e < 4; e++) {
                    const float* ab = &aLS[s * 32 + q * 8 + 2 * e];
                    float x0 = fast_tanh(ab[0] + blo(bd[s * 4 + e]));
                    float x1 = fast_tanh(ab[1] + bhi(bd[s * 4 + e]));
                    ((unsigned int*)&pkd.u4)[e] = pk2(x0, x1);
                }
                afr[s] = pkd.v;
            }
        }

        // 3) stage A: X2^T = Wi2 * X1^T, C-init = bias. D[row=n][col=j]
        f32x4 accA[4];
        #pragma unroll
        for (int nb = 0; nb < 4; nb++) {
            f32x4 acc = b2q[nb];
            #pragma unroll
            for (int s = 0; s < 2; s++) {
                bf16x8 w2f = *(const bf16x8*)(&W2ls[(nb * 16 + m) * 72 + s * 32 + q * 8]);
                acc = __builtin_amdgcn_mfma_f32_16x16x32_bf16(w2f, afr[s], acc, 0, 0, 0);
            }
            accA[nb] = acc;
        }
        // epilogue A: x2s = fac_j * tanh(acc)  -> [j][n] LDS, b64 writes
        #pragma unroll
        for (int nb = 0; nb < 4; nb++) {
            float t0 = fast_tanh(accA[nb][0]) * facm;
            float t1 = fast_tanh(accA[nb][1]) * facm;
            float t2 = fast_tanh(accA[nb][2]) * facm;
            float t3 = fast_tanh(accA[nb][3]) * facm;
            uint2 pk; pk.x = pk2(t0, t1); pk.y = pk2(t2, t3);
            *(uint2*)(&xw[m * 72 + nb * 16 + q * 4]) = pk;
        }

        // 4) stage B: accK += X2s @ Wi3^T  (persistent MFMA accumulator)
        {
            bf16x8 x2f[2];
            #pragma unroll
            for (int s = 0; s < 2; s++)
                x2f[s] = *(const bf16x8*)(&xw[m * 72 + s * 32 + q * 8]);
            #pragma unroll
            for (int lb = 0; lb < 2; lb++) {
                #pragma unroll
                for (int s = 0; s < 2; s++) {
                    bf16x8 w3f = *(const bf16x8*)(&W3ls[(lb * 16 + m) * 72 + s * 32 + q * 8]);
                    accK[lb] = __builtin_amdgcn_mfma_f32_16x16x32_bf16(x2f[s], w3f, accK[lb], 0, 0, 0);
                }
            }
        }

        // 5) stage C: quantum-term partials (diff=0 at j==i -> auto-masked)
        #pragma unroll
        for (int lb = 0; lb < 2; lb++) {
            float u = 0.f, v = 0.f;
            #pragma unroll
            for (int r = 0; r < 4; r++) {
                uint2 jv = jt[lb * 4 + r];
                float hj = blo(jv.x), cj = bhi(jv.x);
                float pjc = blo(jv.y), pjs = bhi(jv.y);
                float coh = fast_sigmoid(cibv[lb] + cj);
                float cd  = coh * (hiv[lb] - hj);
                u = fmaf(cd, pjc, u);
                v = fmaf(cd, pjs, v);
            }
            aU[lb] += u; aV[lb] += v;
        }
    };

    #pragma unroll 1
    for (int T = 0; T < 16; T += 2) {
        body(T,     hvA, b0A, b1A, hvB, b0B, b1B);
        body(T + 1, hvB, b0B, b1B, hvA, b0A, b1A);
    }

    // ---- final reductions ----
    float T1[2];
    #pragma unroll
    for (int lb = 0; lb < 2; lb++) {
        T1[lb] = (accK[lb][0] + accK[lb][1]) + (accK[lb][2] + accK[lb][3]);
        T1[lb] += __shfl_xor(T1[lb], 16); T1[lb] += __shfl_xor(T1[lb], 32);
        aU[lb] += __shfl_xor(aU[lb], 16); aU[lb] += __shfl_xor(aU[lb], 32);
        aV[lb] += __shfl_xor(aV[lb], 16); aV[lb] += __shfl_xor(aV[lb], 32);
    }
    sumfac += __shfl_xor(sumfac, 1);  sumfac += __shfl_xor(sumfac, 2);
    sumfac += __shfl_xor(sumfac, 4);  sumfac += __shfl_xor(sumfac, 8);
    sumfac += __shfl_xor(sumfac, 16); sumfac += __shfl_xor(sumfac, 32);
    if (lane < 16) {
        redT[w][m] = T1[0];      redT[w][16 + m] = T1[1];
        redU[w][m] = aU[0];      redU[w][16 + m] = aU[1];
        redV[w][m] = aV[0];      redV[w][16 + m] = aV[1];
    }
    if (lane == 0) sfw[w] = sumfac;
    __syncthreads();
    if (tid < 32) {
        int l = tid;
        float t1 = (redT[0][l] + redT[1][l]) + (redT[2][l] + redT[3][l]);
        float uu = (redU[0][l] + redU[1][l]) + (redU[2][l] + redU[3][l]);
        float vv = (redV[0][l] + redV[1][l]) + (redV[2][l] + redV[3][l]);
        float sf = (sfw[0] + sfw[1]) + (sfw[2] + sfw[3]);
        uint2 jti = *(const uint2*)(wsu + U_JT + (i * 32 + l) * 4);
        float pic = blo(jti.y), pis = bhi(jti.y);
        float isum = t1 + sf * ws[WS_BI3 + l] - (pic * uu + pis * vv);
        out[i * 33 + l] = 0.5f * ws[WS_SELF + i * 32 + l] + 0.3f * isum;
        redT[0][l] = fabsf(isum);
    }
    __syncthreads();
    if (tid == 0) {
        float s = 0.f;
        #pragma unroll
        for (int l = 0; l < 32; l++) s += redT[0][l];
        out[i * 33 + 32] = 0.1f + 0.05f * s;
    }
}

extern "C" void kernel_launch(void* const* d_in, const int* in_sizes, int n_in,
                              void* d_out, int out_size, void* d_ws, size_t ws_size,
                              hipStream_t stream) {
    const float* state   = (const float*)d_in[0];
    const float* Ws1     = (const float*)d_in[1];
    const float* bs1     = (const float*)d_in[2];
    const float* Ws2     = (const float*)d_in[3];
    const float* bs2     = (const float*)d_in[4];
    const float* Ws3     = (const float*)d_in[5];
    const float* bs3     = (const float*)d_in[6];
    const float* Wi1     = (const float*)d_in[7];
    const float* bi1     = (const float*)d_in[8];
    const float* Wi2     = (const float*)d_in[9];
    const float* bi2     = (const float*)d_in[10];
    const float* Wi3     = (const float*)d_in[11];
    const float* bi3     = (const float*)d_in[12];
    const float* phase_w = (const float*)d_in[13];
    const float* Wc      = (const float*)d_in[14];
    const float* bc      = (const float*)d_in[15];
    const float* aggr    = (const float*)d_in[16];

    float* ws = (float*)d_ws;
    unsigned short* wsu = (unsigned short*)(ws + WS_FEND);
    float* out = (float*)d_out;

    precompute<<<256, 256, 0, stream>>>(state, Ws1, bs1, Ws2, bs2, Ws3, bs3,
                                        Wi1, bi1, Wi2, bi2, Wi3, bi3,
                                        phase_w, Wc, bc, aggr, ws, wsu);
    pair_kernel<<<NN, 256, 0, stream>>>(ws, wsu, out);
}

// Round 8
// 150.131 us; speedup vs baseline: 1.4225x; 1.0295x over previous
//
#include <hip/hip_runtime.h>
#include <hip/hip_bf16.h>
#include <math.h>

#define NN 1024
#define LDIM 32
#define HDIM 64

// ---------------- fp32 workspace layout (float offsets) ----------------
#define WS_SELF 0                        // N*L   self_term [i][l]
#define WS_AA   (WS_SELF + NN*LDIM)      // N*H   a_i [i][h]  (pre-scaled by 2log2e)
#define WS_CI   (WS_AA   + NN*HDIM)      // N*L   -log2e*(ci+bc) [i][l]
#define WS_AGG  (WS_CI   + NN*LDIM)      // N     sigmoid(aggr)
#define WS_BI2  (WS_AGG  + NN)           // H     bi2 * 2log2e
#define WS_BI3  (WS_BI2  + HDIM)         // L     bi3 (unscaled)
#define WS_FEND (WS_BI3  + LDIM)

// ---------------- bf16(u16) region (short offsets from wsu) -------------
#define U_BJB  0                         // N*H   b_j [j][h]  (pre-scaled by 2log2e)
#define U_HJB  (U_BJB + NN*HDIM)         // N*L   h   [j][l]
#define U_JT   (U_HJB + NN*LDIM)         // N*L*4 interleaved {h, -log2e*cj | pc, ps}
#define U_W2B  (U_JT  + NN*LDIM*4)       // H*H   Wi2 [n][k] * 2log2e
#define U_W3B  (U_W2B + HDIM*HDIM)       // L*H   Wi3 [l][k] (unscaled)
#define U_END  (U_W3B + LDIM*HDIM)

// packed-pair transposed weight tables in precompute LDS (uint offsets)
#define PK_W1  0        // 16*64   Ws1
#define PK_W2  1024     // 32*64   Ws2
#define PK_W3  3072     // 32*32   Ws3
#define PK_WI1 4096     // 64*64   Wi1
#define PK_WC  8192     // 32*32   Wc
#define PK_END 9216     // 36 KB

#define K2P  2.88539008f     // 2*log2(e)
#define K1N  (-1.44269504f)  // -log2(e)

typedef __attribute__((ext_vector_type(8))) short bf16x8;
typedef __attribute__((ext_vector_type(4))) float f32x4;

__device__ __forceinline__ float fast_rcp(float x) { return __builtin_amdgcn_rcpf(x); }
__device__ __forceinline__ float fast_tanh(float x) {          // full version (precompute)
    float e = __builtin_amdgcn_exp2f(x * K2P);
    return 1.0f - 2.0f * fast_rcp(e + 1.0f);
}
__device__ __forceinline__ float tanh_pre(float xp) {          // input pre-scaled by 2log2e
    return 1.0f - 2.0f * fast_rcp(__builtin_amdgcn_exp2f(xp) + 1.0f);
}
__device__ __forceinline__ float fast_sigmoid(float x) {       // full version (precompute)
    return fast_rcp(1.0f + __builtin_amdgcn_exp2f(x * K1N));
}
__device__ __forceinline__ float blo(unsigned int u) { union { unsigned int i; float f; } v; v.i = u << 16; return v.f; }
__device__ __forceinline__ float bhi(unsigned int u) { union { unsigned int i; float f; } v; v.i = u & 0xffff0000u; return v.f; }
__device__ __forceinline__ float bf2f(unsigned short u) { union { unsigned int i; float f; } v; v.i = ((unsigned int)u) << 16; return v.f; }
__device__ __forceinline__ unsigned short f2bf(float f) {
    __hip_bfloat16 b = __float2bfloat16(f);
    unsigned short u; __builtin_memcpy(&u, &b, 2); return u;
}
__device__ __forceinline__ unsigned int pk2(float a, float b) {
    float2 t; t.x = a; t.y = b;
    __hip_bfloat162 h = __float22bfloat162_rn(t);
    unsigned int u; __builtin_memcpy(&u, &h, 4); return u;
}

// ------------- kernel 1: precompute (weights packed in-block) -------------
__global__ __launch_bounds__(256) void precompute(
    const float* __restrict__ state,
    const float* __restrict__ Ws1, const float* __restrict__ bs1,
    const float* __restrict__ Ws2, const float* __restrict__ bs2,
    const float* __restrict__ Ws3, const float* __restrict__ bs3,
    const float* __restrict__ Wi1, const float* __restrict__ bi1,
    const float* __restrict__ Wi2, const float* __restrict__ bi2,
    const float* __restrict__ Wi3, const float* __restrict__ bi3,
    const float* __restrict__ phw, const float* __restrict__ Wc,
    const float* __restrict__ bc,  const float* __restrict__ aggr,
    float* __restrict__ ws, unsigned short* __restrict__ wsu) {
    const int tid = threadIdx.x;
    const int w = tid >> 6, t = tid & 63;
    const int i = blockIdx.x * 4 + w;

    __shared__ unsigned int wlds[PK_END];
    __shared__ float shh[4][32], shdh[4][32], sht1[4][64], sht2[4][64];
    __shared__ float shph[4];

    {
        const float2* s1 = (const float2*)Ws1;
        #pragma unroll
        for (int r = 0; r < 4; r++) { int e = tid + r * 256; int f = e >> 4, k2 = e & 15;
            float2 v = s1[e]; wlds[PK_W1 + k2 * 64 + f] = pk2(v.x, v.y); }
        const float2* s2 = (const float2*)Ws2;
        #pragma unroll
        for (int r = 0; r < 8; r++) { int e = tid + r * 256; int f = e >> 5, k2 = e & 31;
            float2 v = s2[e]; wlds[PK_W2 + k2 * 64 + f] = pk2(v.x, v.y); }
        const float2* s3 = (const float2*)Ws3;
        #pragma unroll
        for (int r = 0; r < 4; r++) { int e = tid + r * 256; int f = e >> 5, k2 = e & 31;
            float2 v = s3[e]; wlds[PK_W3 + k2 * 32 + f] = pk2(v.x, v.y); }
        const float2* si = (const float2*)Wi1;
        #pragma unroll
        for (int r = 0; r < 16; r++) { int e = tid + r * 256; int f = e >> 6, c2 = e & 63;
            float2 v = si[e]; wlds[PK_WI1 + c2 * 64 + f] = pk2(v.x, v.y); }
        const float2* sc = (const float2*)Wc;
        #pragma unroll
        for (int r = 0; r < 4; r++) { int e = tid + r * 256; int f = e >> 5, c2 = e & 31;
            float2 v = sc[e]; wlds[PK_WC + c2 * 32 + f] = pk2(v.x, v.y); }
    }
    if (blockIdx.x == 0) {
        #pragma unroll
        for (int r = 0; r < 16; r++) { int e = tid + r * 256; wsu[U_W2B + e] = f2bf(Wi2[e] * K2P); }
        #pragma unroll
        for (int r = 0; r < 8; r++)  { int e = tid + r * 256; wsu[U_W3B + e] = f2bf(Wi3[e]); }
        if (tid < HDIM) ws[WS_BI2 + tid] = bi2[tid] * K2P;
        if (tid < LDIM) ws[WS_BI3 + tid] = bi3[tid];
    }

    float sv = (t < 33) ? state[i * 33 + t] : 0.f;
    if (t < 32) shh[w][t] = sv;
    if (t == 32) shph[w] = sv;
    if (t == 33) ws[WS_AGG + i] = fast_sigmoid(aggr[i]);
    __syncthreads();

    {
        float s = bs1[t];
        const unsigned int* W = wlds + PK_W1;
        #pragma unroll
        for (int k2 = 0; k2 < 16; k2++) {
            unsigned int p = W[k2 * 64 + t];
            s = fmaf(blo(p), shh[w][2 * k2], s);
            s = fmaf(bhi(p), shh[w][2 * k2 + 1], s);
        }
        sht1[w][t] = fast_tanh(s);
    }
    __syncthreads();
    {
        float s = bs2[t];
        const unsigned int* W = wlds + PK_W2;
        #pragma unroll
        for (int k2 = 0; k2 < 32; k2++) {
            unsigned int p = W[k2 * 64 + t];
            s = fmaf(blo(p), sht1[w][2 * k2], s);
            s = fmaf(bhi(p), sht1[w][2 * k2 + 1], s);
        }
        sht2[w][t] = fast_tanh(s);
    }
    __syncthreads();
    if (t < 32) {
        float s = bs3[t];
        const unsigned int* W = wlds + PK_W3;
        #pragma unroll
        for (int k2 = 0; k2 < 32; k2++) {
            unsigned int p = W[k2 * 32 + t];
            s = fmaf(blo(p), sht2[w][2 * k2], s);
            s = fmaf(bhi(p), sht2[w][2 * k2 + 1], s);
        }
        ws[WS_SELF + i * 32 + t] = s;
        shdh[w][t] = s;
    }
    __syncthreads();
    {
        float sa = 0.f, sb = bi1[t];
        const unsigned int* W = wlds + PK_WI1;
        #pragma unroll
        for (int k2 = 0; k2 < 16; k2++) {
            float h0 = shh[w][2 * k2], h1 = shh[w][2 * k2 + 1];
            float d0 = shdh[w][2 * k2], d1 = shdh[w][2 * k2 + 1];
            unsigned int wa  = W[k2 * 64 + t];
            unsigned int wb  = W[(16 + k2) * 64 + t];
            unsigned int wa2 = W[(32 + k2) * 64 + t];
            unsigned int wb2 = W[(48 + k2) * 64 + t];
            sa = fmaf(blo(wa), h0, sa);  sa = fmaf(bhi(wa), h1, sa);
            sb = fmaf(blo(wb), h0, sb);  sb = fmaf(bhi(wb), h1, sb);
            sa = fmaf(blo(wa2), d0, sa); sa = fmaf(bhi(wa2), d1, sa);
            sb = fmaf(blo(wb2), d0, sb); sb = fmaf(bhi(wb2), d1, sb);
        }
        ws[WS_AA + i * 64 + t]  = sa * K2P;          // pre-scaled for tanh_pre
        wsu[U_BJB + i * 64 + t] = f2bf(sb * K2P);
    }
    if (t < 32) {
        float si = 0.f, sj = 0.f;
        const unsigned int* W = wlds + PK_WC;
        #pragma unroll
        for (int m2 = 0; m2 < 16; m2++) {
            float h0 = shh[w][2 * m2], h1 = shh[w][2 * m2 + 1];
            unsigned int wi = W[m2 * 32 + t];
            unsigned int wj = W[(16 + m2) * 32 + t];
            si = fmaf(blo(wi), h0, si); si = fmaf(bhi(wi), h1, si);
            sj = fmaf(blo(wj), h0, sj); sj = fmaf(bhi(wj), h1, sj);
        }
        ws[WS_CI + i * 32 + t] = (si + bc[t]) * K1N; // pre-scaled for rcp(1+exp2)
        float h = shh[w][t];
        wsu[U_HJB + i * 32 + t] = f2bf(h);
        float sc, cc;
        __sincosf(shph[w] * phw[t], &sc, &cc);
        uint2 jt; jt.x = pk2(h, sj * K1N); jt.y = pk2(cc, sc);
        *(uint2*)(wsu + U_JT + (i * 32 + t) * 4) = jt;
    }
}

// ------------- kernel 2: MFMA pairwise core (1 block per i) ---------------
// Diet: all exp-scale multiplies folded into precomputed data; fac folded
// into the epilogue tanh-FMA. Pipelining: per-wave double-buffered x2 tile;
// stage B for tile T-1 runs in body T, so the LDS write->read RAW hazard
// is a full body (~700 cyc) old and off the critical path.
__global__ __launch_bounds__(256) void pair_kernel(
    const float* __restrict__ ws, const unsigned short* __restrict__ wsu,
    float* __restrict__ out) {
    const int i    = blockIdx.x;
    const int tid  = threadIdx.x;
    const int w    = tid >> 6;
    const int lane = tid & 63;
    const int q    = lane >> 4;
    const int m    = lane & 15;
    const int jw   = w * 16;
    const int sub  = lane & 3;

    __shared__ unsigned short W2ls[64 * 72];
    __shared__ unsigned short W3ls[32 * 72];
    __shared__ unsigned short x2ls[4 * 2 * 16 * 72];   // per-wave double buffer
    __shared__ float aLS[64];
    __shared__ float redT[4][32], redU[4][32], redV[4][32];
    __shared__ float sfw[4];

    // ---- setup ----
    if (tid < 64) aLS[tid] = ws[WS_AA + i * 64 + tid];
    {
        int row = tid >> 2, c = (tid & 3) * 16;
        const uint4* s2 = (const uint4*)(wsu + U_W2B + row * 64 + c);
        uint4 d0 = s2[0], d1 = s2[1];
        uint4* dd = (uint4*)(&W2ls[row * 72 + c]);
        dd[0] = d0; dd[1] = d1;
        if (row < 32) {
            const uint4* s3 = (const uint4*)(wsu + U_W3B + row * 64 + c);
            uint4 e0 = s3[0], e1 = s3[1];
            uint4* d3 = (uint4*)(&W3ls[row * 72 + c]);
            d3[0] = e0; d3[1] = e1;
        }
    }
    float hi8[8];
    {
        uint4 hv4 = *(const uint4*)(wsu + U_HJB + i * 32 + sub * 8);
        unsigned int hd[4] = {hv4.x, hv4.y, hv4.z, hv4.w};
        #pragma unroll
        for (int e = 0; e < 4; e++) { hi8[2 * e] = blo(hd[e]); hi8[2 * e + 1] = bhi(hd[e]); }
    }
    f32x4 b2q[4];              // pre-scaled bias slice for MFMA C-init
    #pragma unroll
    for (int nb = 0; nb < 4; nb++) {
        float4 bv = *(const float4*)(ws + WS_BI2 + nb * 16 + q * 4);
        b2q[nb][0] = bv.x; b2q[nb][1] = bv.y; b2q[nb][2] = bv.z; b2q[nb][3] = bv.w;
    }
    float hiv[2], cibv[2];
    #pragma unroll
    for (int lb = 0; lb < 2; lb++) {
        int l = lb * 16 + m;
        hiv[lb]  = bf2f(wsu[U_HJB + i * 32 + l]);
        cibv[lb] = ws[WS_CI + i * 32 + l];        // already has bc, pre-scaled
    }
    const float aggi = ws[WS_AGG + i];
    const float sub0 = (sub == 0) ? 1.0f : 0.0f;

    // ---- streaming pointers + tile-0 prefetch ----
    const unsigned short* hp = wsu + U_HJB + (jw + (lane >> 2)) * 32 + sub * 8;
    const unsigned short* bp = wsu + U_BJB + (jw + m) * 64 + q * 8;
    const unsigned short* jp = wsu + U_JT + ((jw + q * 4) * 32 + m) * 4;

    uint4 hvA = *(const uint4*)hp;
    uint4 b0A = *(const uint4*)bp;
    uint4 b1A = *(const uint4*)(bp + 32);
    uint4 hvB, b0B, b1B;
    __syncthreads();

    // persistent accumulators
    f32x4 accK[2];
    #pragma unroll
    for (int lb = 0; lb < 2; lb++) { accK[lb][0]=0.f; accK[lb][1]=0.f; accK[lb][2]=0.f; accK[lb][3]=0.f; }
    float aU[2] = {0.f, 0.f}, aV[2] = {0.f, 0.f};
    float sumfac = 0.f;

    unsigned short* xb0 = &x2ls[w * 2 * 1152];
    unsigned short* xb1 = xb0 + 1152;

    auto stageB = [&](const unsigned short* xb) {
        bf16x8 x2f[2];
        #pragma unroll
        for (int s = 0; s < 2; s++)
            x2f[s] = *(const bf16x8*)(&xb[m * 72 + s * 32 + q * 8]);
        #pragma unroll
        for (int lb = 0; lb < 2; lb++) {
            #pragma unroll
            for (int s = 0; s < 2; s++) {
                bf16x8 w3f = *(const bf16x8*)(&W3ls[(lb * 16 + m) * 72 + s * 32 + q * 8]);
                accK[lb] = __builtin_amdgcn_mfma_f32_16x16x32_bf16(x2f[s], w3f, accK[lb], 0, 0, 0);
            }
        }
    };

    auto body = [&](int T, uint4 hvc, uint4 b0c, uint4 b1c,
                    uint4& hvn, uint4& b0n, uint4& b1n,
                    unsigned short* xcur, const unsigned short* xprev) {
        // prefetch next tile's h/b
        hp += 2048; bp += 4096;
        hvn = *(const uint4*)hp;
        b0n = *(const uint4*)bp;
        b1n = *(const uint4*)(bp + 32);
        // jt loads for CURRENT tile (consumed at body end)
        uint2 jt[8];
        #pragma unroll
        for (int r = 0; r < 4; r++) {
            jt[r]     = *(const uint2*)(jp + r * 128);
            jt[4 + r] = *(const uint2*)(jp + 64 + r * 128);
        }
        jp += 8192;

        // deferred stage B for previous tile (LDS data a full body old)
        if (T > 0) stageB(xprev);

        // 1) fac (lane owns j = T*64 + jw + (lane>>2)); zeroed at j==i
        float facm;
        {
            unsigned int hd[4] = {hvc.x, hvc.y, hvc.z, hvc.w};
            float s = 0.f;
            #pragma unroll
            for (int e = 0; e < 4; e++) {
                float d0 = hi8[2 * e]     - blo(hd[e]);
                float d1 = hi8[2 * e + 1] - bhi(hd[e]);
                s = fmaf(d0, d0, s); s = fmaf(d1, d1, s);
            }
            s += __shfl_xor(s, 1); s += __shfl_xor(s, 2);
            int jj = T * 64 + jw + (lane >> 2);
            // rsq(s) == 1/(sqrt(s)+1e-6) to bf16 precision; s->0 clamps to 2 same as ref
            float facown = fminf(__builtin_amdgcn_rsqf(s), 2.0f) * aggi;
            facown = (jj == i) ? 0.0f : facown;
            sumfac = fmaf(sub0, facown, sumfac);
            facm = __shfl(facown, 4 * m);
        }
        const float fm2 = -2.0f * facm;

        // 2) x1 B-fragments: tanh via pre-scaled inputs (no multiplies)
        bf16x8 afr[2];
        {
            unsigned int bd[8] = {b0c.x, b0c.y, b0c.z, b0c.w, b1c.x, b1c.y, b1c.z, b1c.w};
            #pragma unroll
            for (int s = 0; s < 2; s++) {
                union { uint4 u4; bf16x8 v; } pkd;
                #pragma unroll
                for (int e = 0; e < 4; e++) {
                    const float* ab = &aLS[s * 32 + q * 8 + 2 * e];
                    float x0 = tanh_pre(ab[0] + blo(bd[s * 4 + e]));
                    float x1 = tanh_pre(ab[1] + bhi(bd[s * 4 + e]));
                    ((unsigned int*)&pkd.u4)[e] = pk2(x0, x1);
                }
                afr[s] = pkd.v;
            }
        }

        // 3) stage A: X2^T = Wi2' * X1^T, C-init = scaled bias
        f32x4 accA[4];
        #pragma unroll
        for (int nb = 0; nb < 4; nb++) {
            f32x4 acc = b2q[nb];
            #pragma unroll
            for (int s = 0; s < 2; s++) {
                bf16x8 w2f = *(const bf16x8*)(&W2ls[(nb * 16 + m) * 72 + s * 32 + q * 8]);
                acc = __builtin_amdgcn_mfma_f32_16x16x32_bf16(w2f, afr[s], acc, 0, 0, 0);
            }
            accA[nb] = acc;
        }
        // epilogue A: x2s = fac * tanh = fma(-2fac, rcp(exp2(acc)+1), fac)
        #pragma unroll
        for (int nb = 0; nb < 4; nb++) {
            float r0 = fast_rcp(__builtin_amdgcn_exp2f(accA[nb][0]) + 1.0f);
            float r1 = fast_rcp(__builtin_amdgcn_exp2f(accA[nb][1]) + 1.0f);
            float r2 = fast_rcp(__builtin_amdgcn_exp2f(accA[nb][2]) + 1.0f);
            float r3 = fast_rcp(__builtin_amdgcn_exp2f(accA[nb][3]) + 1.0f);
            float t0 = fmaf(fm2, r0, facm), t1 = fmaf(fm2, r1, facm);
            float t2 = fmaf(fm2, r2, facm), t3 = fmaf(fm2, r3, facm);
            uint2 pk; pk.x = pk2(t0, t1); pk.y = pk2(t2, t3);
            *(uint2*)(&xcur[m * 72 + nb * 16 + q * 4]) = pk;
        }

        // 5) stage C: quantum-term partials (pre-scaled sigmoid, diff=0 at j==i)
        #pragma unroll
        for (int lb = 0; lb < 2; lb++) {
            float u = 0.f, v = 0.f;
            #pragma unroll
            for (int r = 0; r < 4; r++) {
                uint2 jv = jt[lb * 4 + r];
                float hj = blo(jv.x), cj = bhi(jv.x);
                float pjc = blo(jv.y), pjs = bhi(jv.y);
                float coh = fast_rcp(1.0f + __builtin_amdgcn_exp2f(cibv[lb] + cj));
                float cd  = coh * (hiv[lb] - hj);
                u = fmaf(cd, pjc, u);
                v = fmaf(cd, pjs, v);
            }
            aU[lb] += u; aV[lb] += v;
        }
    };

    #pragma unroll 1
    for (int T = 0; T < 16; T += 2) {
        body(T,     hvA, b0A, b1A, hvB, b0B, b1B, xb0, xb1);
        body(T + 1, hvB, b0B, b1B, hvA, b0A, b1A, xb1, xb0);
    }
    stageB(xb1);   // tile 15

    // ---- final reductions ----
    float T1[2];
    #pragma unroll
    for (int lb = 0; lb < 2; lb++) {
        T1[lb] = (accK[lb][0] + accK[lb][1]) + (accK[lb][2] + accK[lb][3]);
        T1[lb] += __shfl_xor(T1[lb], 16); T1[lb] += __shfl_xor(T1[lb], 32);
        aU[lb] += __shfl_xor(aU[lb], 16); aU[lb] += __shfl_xor(aU[lb], 32);
        aV[lb] += __shfl_xor(aV[lb], 16); aV[lb] += __shfl_xor(aV[lb], 32);
    }
    sumfac += __shfl_xor(sumfac, 1);  sumfac += __shfl_xor(sumfac, 2);
    sumfac += __shfl_xor(sumfac, 4);  sumfac += __shfl_xor(sumfac, 8);
    sumfac += __shfl_xor(sumfac, 16); sumfac += __shfl_xor(sumfac, 32);
    if (lane < 16) {
        redT[w][m] = T1[0];      redT[w][16 + m] = T1[1];
        redU[w][m] = aU[0];      redU[w][16 + m] = aU[1];
        redV[w][m] = aV[0];      redV[w][16 + m] = aV[1];
    }
    if (lane == 0) sfw[w] = sumfac;
    __syncthreads();
    if (tid < 32) {
        int l = tid;
        float t1 = (redT[0][l] + redT[1][l]) + (redT[2][l] + redT[3][l]);
        float uu = (redU[0][l] + redU[1][l]) + (redU[2][l] + redU[3][l]);
        float vv = (redV[0][l] + redV[1][l]) + (redV[2][l] + redV[3][l]);
        float sf = (sfw[0] + sfw[1]) + (sfw[2] + sfw[3]);
        uint2 jti = *(const uint2*)(wsu + U_JT + (i * 32 + l) * 4);
        float pic = blo(jti.y), pis = bhi(jti.y);
        float isum = t1 + sf * ws[WS_BI3 + l] - (pic * uu + pis * vv);
        out[i * 33 + l] = 0.5f * ws[WS_SELF + i * 32 + l] + 0.3f * isum;
        redT[0][l] = fabsf(isum);
    }
    __syncthreads();
    if (tid == 0) {
        float s = 0.f;
        #pragma unroll
        for (int l = 0; l < 32; l++) s += redT[0][l];
        out[i * 33 + 32] = 0.1f + 0.05f * s;
    }
}

extern "C" void kernel_launch(void* const* d_in, const int* in_sizes, int n_in,
                              void* d_out, int out_size, void* d_ws, size_t ws_size,
                              hipStream_t stream) {
    const float* state   = (const float*)d_in[0];
    const float* Ws1     = (const float*)d_in[1];
    const float* bs1     = (const float*)d_in[2];
    const float* Ws2     = (const float*)d_in[3];
    const float* bs2     = (const float*)d_in[4];
    const float* Ws3     = (const float*)d_in[5];
    const float* bs3     = (const float*)d_in[6];
    const float* Wi1     = (const float*)d_in[7];
    const float* bi1     = (const float*)d_in[8];
    const float* Wi2     = (const float*)d_in[9];
    const float* bi2     = (const float*)d_in[10];
    const float* Wi3     = (const float*)d_in[11];
    const float* bi3     = (const float*)d_in[12];
    const float* phase_w = (const float*)d_in[13];
    const float* Wc      = (const float*)d_in[14];
    const float* bc      = (const float*)d_in[15];
    const float* aggr    = (const float*)d_in[16];

    float* ws = (float*)d_ws;
    unsigned short* wsu = (unsigned short*)(ws + WS_FEND);
    float* out = (float*)d_out;

    precompute<<<256, 256, 0, stream>>>(state, Ws1, bs1, Ws2, bs2, Ws3, bs3,
                                        Wi1, bi1, Wi2, bi2, Wi3, bi3,
                                        phase_w, Wc, bc, aggr, ws, wsu);
    pair_kernel<<<NN, 256, 0, stream>>>(ws, wsu, out);
}